// Round 7
// baseline (2144.552 us; speedup 1.0000x reference)
//
#include <hip/hip_runtime.h>

// Primitive-equations block stepper, gfx950 — R7.
// Key change vs R6: the double stencil (Laplacian = D1∘D1) is fused into a
// single 9x9 stencil with precomputed per-output-row weights
//   W2[h][m][n] = sum_{a,c,b,d: clip(clip(h+a-2)+c-2)-h=m, b+d=n}
//                 P1q[h][a,b] * P1q[clip(h+a-2)][c,d]
// (binned by clipped source row -> pole handling exact). This deletes the
// d1S LDS intermediate entirely: one barrier, LDS = S4 only (28 KB ->
// 4-5 blocks/CU), ~115 LDS instr/thread vs ~160.
// Kernels: pe_tab_pq (P0q/P1q padded tables), pe_tab_w2 (9x9 weights),
// pe_pass1 (all horizontal work), pe_pass2 (vertical coupling).

constexpr int Kz = 8, Hh = 361, Ww = 720;
constexpr int HW = Hh * Ww;              // 259920
constexpr int OFF_DT = Kz * HW * 2;      // 4158720
constexpr int OFF_DQ = OFF_DT + Kz * HW; // 6238080

constexpr int TH = 16, TW = 64;          // outputs per block
constexpr int SH = TH + 8, SW4 = TW + 8; // staged region 24 x 72 points
constexpr int SW4P = 73;                 // S4 row stride (odd mod 8 -> banks)
constexpr int PQROW = 40;                // P-table row stride: 5 a-groups x 8
constexpr int W2ROW = 108;               // W2 row stride: 9 m-groups x 12

__device__ __forceinline__ int clipH(int x) {
  return x < 0 ? 0 : (x > Hh - 1 ? Hh - 1 : x);
}

#define FMA4(acc, s, v)                                                        \
  do {                                                                         \
    acc.x = fmaf((s), (v).x, acc.x);                                           \
    acc.y = fmaf((s), (v).y, acc.y);                                           \
    acc.z = fmaf((s), (v).z, acc.z);                                           \
    acc.w = fmaf((s), (v).w, acc.w);                                           \
  } while (0)

#define LAP9(acc, A, B, C, D, E, F, G, H, I)                                   \
  do {                                                                         \
    FMA4(acc, wa.x, A); FMA4(acc, wa.y, B); FMA4(acc, wa.z, C);                \
    FMA4(acc, wa.w, D); FMA4(acc, wb.x, E); FMA4(acc, wb.y, F);                \
    FMA4(acc, wb.z, G); FMA4(acc, wb.w, H); FMA4(acc, w8, I);                  \
  } while (0)

#define ROW5S(acc, q0, q1, q2, q3, q4, a, b, c, d, e)                          \
  acc = fmaf(q0, a, fmaf(q1, b, fmaf(q2, c, fmaf(q3, d, fmaf(q4, e, acc)))))

// ---------------------------------------------------- P0q/P1q tables --------
__global__ __launch_bounds__(256) void pe_tab_pq(
    const float* __restrict__ psi,
    const float* __restrict__ quad,
    float* __restrict__ P0g,
    float* __restrict__ P1g)
{
  int idx = blockIdx.x * 256 + threadIdx.x;   // h*40 + a*8 + b
  if (idx >= Hh * PQROW) return;
  int h = idx / PQROW, o = idx - h * PQROW;
  int a = o >> 3, b = o & 7;
  float v0 = 0.f, v1 = 0.f;
  if (b < 5) {
    #pragma unroll
    for (int kk = 0; kk < 5; ++kk) {
      v0 += psi[kk * (2 * Hh * 25) + h * 25 + a * 5 + b];
      v1 += psi[kk * (2 * Hh * 25) + Hh * 25 + h * 25 + a * 5 + b];
    }
    float qv = quad[clipH(h + a - 2)];
    v0 *= qv; v1 *= qv;
  }
  P0g[idx] = v0;
  P1g[idx] = v1;
}

// ---------------------------------------------------- W2 9x9 weights --------
__global__ __launch_bounds__(256) void pe_tab_w2(
    const float* __restrict__ P1g,
    float* __restrict__ W2g)
{
  int idx = blockIdx.x * 256 + threadIdx.x;   // h*9 + mi
  if (idx >= Hh * 9) return;
  int h = idx / 9, mi = idx - h * 9;
  int m = mi - 4;
  float n0=0,n1=0,n2=0,n3=0,n4=0,n5=0,n6=0,n7=0,n8=0;
  for (int a = 0; a < 5; ++a) {
    int ra = clipH(h + a - 2);
    float xa0 = P1g[h * PQROW + a * 8 + 0];
    float xa1 = P1g[h * PQROW + a * 8 + 1];
    float xa2 = P1g[h * PQROW + a * 8 + 2];
    float xa3 = P1g[h * PQROW + a * 8 + 3];
    float xa4 = P1g[h * PQROW + a * 8 + 4];
    for (int c = 0; c < 5; ++c) {
      int rc = clipH(ra + c - 2);
      if (rc - h != m) continue;
      float y0 = P1g[ra * PQROW + c * 8 + 0];
      float y1 = P1g[ra * PQROW + c * 8 + 1];
      float y2 = P1g[ra * PQROW + c * 8 + 2];
      float y3 = P1g[ra * PQROW + c * 8 + 3];
      float y4 = P1g[ra * PQROW + c * 8 + 4];
      n0 += xa0*y0;
      n1 += xa0*y1 + xa1*y0;
      n2 += xa0*y2 + xa1*y1 + xa2*y0;
      n3 += xa0*y3 + xa1*y2 + xa2*y1 + xa3*y0;
      n4 += xa0*y4 + xa1*y3 + xa2*y2 + xa3*y1 + xa4*y0;
      n5 += xa1*y4 + xa2*y3 + xa3*y2 + xa4*y1;
      n6 += xa2*y4 + xa3*y3 + xa4*y2;
      n7 += xa3*y4 + xa4*y3;
      n8 += xa4*y4;
    }
  }
  float* w = W2g + h * W2ROW + mi * 12;
  w[0]=n0; w[1]=n1; w[2]=n2; w[3]=n3; w[4]=n4;
  w[5]=n5; w[6]=n6; w[7]=n7; w[8]=n8; w[9]=0.f; w[10]=0.f; w[11]=0.f;
}

// ---------------------------------------------------------------- pass 1 ----
__global__ __launch_bounds__(256, 4) void pe_pass1(
    const float2* __restrict__ uv,
    const float*  __restrict__ Tg,
    const float*  __restrict__ qg,
    const float*  __restrict__ P0g,
    const float*  __restrict__ P1g,
    const float*  __restrict__ W2g,
    const float*  __restrict__ f_cor,
    const float*  __restrict__ delta_p,
    float* __restrict__ out,
    float2* __restrict__ ws)
{
  __shared__ float4 S4[SH][SW4P];       // (u,v,T,q), 28.0 KB — only LDS

  const int tid = threadIdx.x;
  const int tx = tid & 15;              // thread col (owns 4 outputs)
  const int ty = tid >> 4;              // thread row
  const int w0 = blockIdx.x * TW;
  const int h0 = blockIdx.y * TH;
  const int k  = blockIdx.z;

  // ---- stage (u,v,T,q) as float4 with +-4 halo (clip lat, wrap lon) ----
  for (int idx = tid; idx < SH * SW4; idx += 256) {
    int rr = idx / SW4, cc = idx - rr * SW4;
    int pr = clipH(h0 + rr - 4);
    int pc = w0 + cc - 4;
    pc = pc < 0 ? pc + Ww : (pc >= Ww ? pc - Ww : pc);
    int g = (k * Hh + pr) * Ww + pc;
    float2 uvv = uv[g];
    S4[rr][cc] = make_float4(uvv.x, uvv.y, Tg[g], qg[g]);
  }
  __syncthreads();

  const int h = h0 + ty;
  const int hc = h < Hh ? h : (Hh - 1);
  const int wbase = w0 + tx * 4;
  const float f = f_cor[hc];
  const float invR = (float)(1.0 / 6371000.0);
  const float halfInvR = 0.5f * invR;
  const float cL = 200000.0f * invR * invR;
  const float* W2r = W2g + hc * W2ROW;
  const float* P1r = P1g + hc * PQROW;
  const float* P0r = P0g + hc * PQROW;

  float4 lp0 = {0,0,0,0}, lp1 = {0,0,0,0}, lp2 = {0,0,0,0}, lp3 = {0,0,0,0};
  float dvC0=0,dvC1=0,dvC2=0,dvC3=0;   // D1(v) at centers
  float dTC0=0,dTC1=0,dTC2=0,dTC3=0;   // D1(T)
  float dqC0=0,dqC1=0,dqC2=0,dqC3=0;   // D1(q)
  float dk0=0,dk1=0,dk2=0,dk3=0;       // D1(u^2+v^2)
  float du0=0,du1=0,du2=0,du3=0;       // D0(u)
  float2 c0, c1, c2, c3;               // center (u,v)

  #pragma unroll
  for (int m = -4; m <= 4; ++m) {
    int rr = clipH(hc + m) - h0 + 4;
    const float4* srow = &S4[rr][tx * 4];
    float4 s0 = srow[0], s1 = srow[1], s2 = srow[2],  s3 = srow[3];
    float4 s4 = srow[4], s5 = srow[5], s6 = srow[6],  s7 = srow[7];
    float4 s8 = srow[8], s9 = srow[9], s10 = srow[10], s11 = srow[11];

    float4 wa = *(const float4*)(W2r + (m + 4) * 12);
    float4 wb = *(const float4*)(W2r + (m + 4) * 12 + 4);
    float w8 = W2r[(m + 4) * 12 + 8];
    LAP9(lp0, s0, s1, s2, s3, s4, s5, s6, s7, s8);
    LAP9(lp1, s1, s2, s3, s4, s5, s6, s7, s8, s9);
    LAP9(lp2, s2, s3, s4, s5, s6, s7, s8, s9, s10);
    LAP9(lp3, s3, s4, s5, s6, s7, s8, s9, s10, s11);

    if (m >= -2 && m <= 2) {            // compile-time under full unroll
      const int a = m + 2;
      float4 pa = *(const float4*)(P1r + a * 8);
      float p4 = P1r[a * 8 + 4];
      ROW5S(dvC0, pa.x, pa.y, pa.z, pa.w, p4, s2.y, s3.y, s4.y, s5.y, s6.y);
      ROW5S(dvC1, pa.x, pa.y, pa.z, pa.w, p4, s3.y, s4.y, s5.y, s6.y, s7.y);
      ROW5S(dvC2, pa.x, pa.y, pa.z, pa.w, p4, s4.y, s5.y, s6.y, s7.y, s8.y);
      ROW5S(dvC3, pa.x, pa.y, pa.z, pa.w, p4, s5.y, s6.y, s7.y, s8.y, s9.y);
      ROW5S(dTC0, pa.x, pa.y, pa.z, pa.w, p4, s2.z, s3.z, s4.z, s5.z, s6.z);
      ROW5S(dTC1, pa.x, pa.y, pa.z, pa.w, p4, s3.z, s4.z, s5.z, s6.z, s7.z);
      ROW5S(dTC2, pa.x, pa.y, pa.z, pa.w, p4, s4.z, s5.z, s6.z, s7.z, s8.z);
      ROW5S(dTC3, pa.x, pa.y, pa.z, pa.w, p4, s5.z, s6.z, s7.z, s8.z, s9.z);
      ROW5S(dqC0, pa.x, pa.y, pa.z, pa.w, p4, s2.w, s3.w, s4.w, s5.w, s6.w);
      ROW5S(dqC1, pa.x, pa.y, pa.z, pa.w, p4, s3.w, s4.w, s5.w, s6.w, s7.w);
      ROW5S(dqC2, pa.x, pa.y, pa.z, pa.w, p4, s4.w, s5.w, s6.w, s7.w, s8.w);
      ROW5S(dqC3, pa.x, pa.y, pa.z, pa.w, p4, s5.w, s6.w, s7.w, s8.w, s9.w);
      float k2 = fmaf(s2.y, s2.y, s2.x * s2.x);
      float k3 = fmaf(s3.y, s3.y, s3.x * s3.x);
      float k4 = fmaf(s4.y, s4.y, s4.x * s4.x);
      float k5 = fmaf(s5.y, s5.y, s5.x * s5.x);
      float k6 = fmaf(s6.y, s6.y, s6.x * s6.x);
      float k7 = fmaf(s7.y, s7.y, s7.x * s7.x);
      float k8 = fmaf(s8.y, s8.y, s8.x * s8.x);
      float k9 = fmaf(s9.y, s9.y, s9.x * s9.x);
      ROW5S(dk0, pa.x, pa.y, pa.z, pa.w, p4, k2, k3, k4, k5, k6);
      ROW5S(dk1, pa.x, pa.y, pa.z, pa.w, p4, k3, k4, k5, k6, k7);
      ROW5S(dk2, pa.x, pa.y, pa.z, pa.w, p4, k4, k5, k6, k7, k8);
      ROW5S(dk3, pa.x, pa.y, pa.z, pa.w, p4, k5, k6, k7, k8, k9);
      float4 pb = *(const float4*)(P0r + a * 8);
      float pb4 = P0r[a * 8 + 4];
      ROW5S(du0, pb.x, pb.y, pb.z, pb.w, pb4, s2.x, s3.x, s4.x, s5.x, s6.x);
      ROW5S(du1, pb.x, pb.y, pb.z, pb.w, pb4, s3.x, s4.x, s5.x, s6.x, s7.x);
      ROW5S(du2, pb.x, pb.y, pb.z, pb.w, pb4, s4.x, s5.x, s6.x, s7.x, s8.x);
      ROW5S(du3, pb.x, pb.y, pb.z, pb.w, pb4, s5.x, s6.x, s7.x, s8.x, s9.x);
    }
    if (m == 0) {
      c0 = make_float2(s4.x, s4.y);
      c1 = make_float2(s5.x, s5.y);
      c2 = make_float2(s6.x, s6.y);
      c3 = make_float2(s7.x, s7.y);
    }
  }

  if (h < Hh && wbase < Ww) {
    const float dpk = delta_p[k];
    float4 duvA, duvB, dTv, dqv, wsA, wsB;
    {
      float coef1 = fmaf(du0, invR, -f);
      duvA.x = fmaf(-coef1, c0.y, cL * lp0.x);
      duvA.y = fmaf(coef1, c0.x, -halfInvR * dk0) + cL * lp0.y;
      dTv.x = -(invR * dTC0) * c0.y + cL * lp0.z;
      dqv.x = fmaf(-(invR * dqC0), c0.y, cL * lp0.w);
      wsA.x = invR * dvC0 * dpk; wsA.y = dTC0;
    }
    {
      float coef1 = fmaf(du1, invR, -f);
      duvA.z = fmaf(-coef1, c1.y, cL * lp1.x);
      duvA.w = fmaf(coef1, c1.x, -halfInvR * dk1) + cL * lp1.y;
      dTv.y = -(invR * dTC1) * c1.y + cL * lp1.z;
      dqv.y = fmaf(-(invR * dqC1), c1.y, cL * lp1.w);
      wsA.z = invR * dvC1 * dpk; wsA.w = dTC1;
    }
    {
      float coef1 = fmaf(du2, invR, -f);
      duvB.x = fmaf(-coef1, c2.y, cL * lp2.x);
      duvB.y = fmaf(coef1, c2.x, -halfInvR * dk2) + cL * lp2.y;
      dTv.z = -(invR * dTC2) * c2.y + cL * lp2.z;
      dqv.z = fmaf(-(invR * dqC2), c2.y, cL * lp2.w);
      wsB.x = invR * dvC2 * dpk; wsB.y = dTC2;
    }
    {
      float coef1 = fmaf(du3, invR, -f);
      duvB.z = fmaf(-coef1, c3.y, cL * lp3.x);
      duvB.w = fmaf(coef1, c3.x, -halfInvR * dk3) + cL * lp3.y;
      dTv.w = -(invR * dTC3) * c3.y + cL * lp3.z;
      dqv.w = fmaf(-(invR * dqC3), c3.y, cL * lp3.w);
      wsB.z = invR * dvC3 * dpk; wsB.w = dTC3;
    }
    const int gidx = (k * Hh + h) * Ww + wbase;
    float4* o4 = (float4*)out;
    o4[gidx >> 1] = duvA;
    o4[(gidx >> 1) + 1] = duvB;
    *(float4*)&out[OFF_DT + gidx] = dTv;
    *(float4*)&out[OFF_DQ + gidx] = dqv;
    float4* w4 = (float4*)ws;
    w4[gidx >> 1] = wsA;
    w4[(gidx >> 1) + 1] = wsB;
  }
}

// ---------------------------------------------------------------- pass 2 ----
__global__ __launch_bounds__(256) void pe_pass2(
    const float* __restrict__ Tg,
    const float* __restrict__ p_levels,
    const float2* __restrict__ ws,
    float* __restrict__ out)
{
  int i4 = blockIdx.x * 256 + threadIdx.x;   // quad index (4 points/thread)
  if (i4 >= HW / 4) return;
  const float invR = (float)(1.0 / 6371000.0);
  const float RCP = (float)(287.0 / 1004.0);

  float pl[Kz];
  #pragma unroll
  for (int k = 0; k < Kz; ++k) pl[k] = p_levels[k];

  const float4* T4 = (const float4*)Tg;
  const float4* ws4 = (const float4*)ws;
  float4* o4 = (float4*)out;
  float4* dT4 = (float4*)(out + OFF_DT);

  float4 cum = {0,0,0,0}, sumT = {0,0,0,0};
  float4 Tm = {0,0,0,0}, Tc = T4[i4];

  #pragma unroll
  for (int k = 0; k < Kz; ++k) {
    float4 Tp = (k < Kz - 1) ? T4[(k + 1) * (HW / 4) + i4] : make_float4(0,0,0,0);
    float4 wa = ws4[k * (HW / 2) + 2 * i4];
    float4 wb = ws4[k * (HW / 2) + 2 * i4 + 1];
    float om0 = fmaf(0.5f, wa.x, cum.x); cum.x += wa.x;
    float om1 = fmaf(0.5f, wa.z, cum.y); cum.y += wa.z;
    float om2 = fmaf(0.5f, wb.x, cum.z); cum.z += wb.x;
    float om3 = fmaf(0.5f, wb.z, cum.w); cum.w += wb.z;

    float4 dTdp;
    if (k == 0) {
      float idp = 1.f / (pl[1] - pl[0]);
      dTdp.x = (Tp.x - Tc.x) * idp; dTdp.y = (Tp.y - Tc.y) * idp;
      dTdp.z = (Tp.z - Tc.z) * idp; dTdp.w = (Tp.w - Tc.w) * idp;
    } else if (k == Kz - 1) {
      float idp = 1.f / (pl[Kz - 1] - pl[Kz - 2]);
      dTdp.x = (Tc.x - Tm.x) * idp; dTdp.y = (Tc.y - Tm.y) * idp;
      dTdp.z = (Tc.z - Tm.z) * idp; dTdp.w = (Tc.w - Tm.w) * idp;
    } else {
      float idp = 1.f / (pl[k + 1] - pl[k - 1]);
      dTdp.x = (Tp.x - Tm.x) * idp; dTdp.y = (Tp.y - Tm.y) * idp;
      dTdp.z = (Tp.z - Tm.z) * idp; dTdp.w = (Tp.w - Tm.w) * idp;
    }
    float iplk = RCP / pl[k];
    float4 dt = dT4[k * (HW / 4) + i4];
    dt.x += om0 * fmaf(iplk, Tc.x, -dTdp.x);
    dt.y += om1 * fmaf(iplk, Tc.y, -dTdp.y);
    dt.z += om2 * fmaf(iplk, Tc.z, -dTdp.z);
    dt.w += om3 * fmaf(iplk, Tc.w, -dTdp.w);
    dT4[k * (HW / 4) + i4] = dt;

    float4 oa = o4[k * (HW / 2) + 2 * i4];
    float4 ob = o4[k * (HW / 2) + 2 * i4 + 1];
    oa.y += sumT.x; oa.w += sumT.y;
    ob.y += sumT.z; ob.w += sumT.w;
    o4[k * (HW / 2) + 2 * i4] = oa;
    o4[k * (HW / 2) + 2 * i4 + 1] = ob;

    if (k < Kz - 1) {
      float c = -287.0f * logf(pl[k] / pl[k + 1]) * invR;
      sumT.x = fmaf(c, wa.y, sumT.x);
      sumT.y = fmaf(c, wa.w, sumT.y);
      sumT.z = fmaf(c, wb.y, sumT.z);
      sumT.w = fmaf(c, wb.w, sumT.w);
    }
    Tm = Tc; Tc = Tp;
  }
}

// ------------------------------------------------- fallback fused kernel ----
constexpr int FTH = 16, FTW = 16;
constexpr int FSH = FTH + 8, FSW = FTW + 8;
constexpr int FEH = FTH + 4, FEW = FTW + 4;
constexpr int FSWp = FSW + 1, FEWp = FEW + 1;

__global__ __launch_bounds__(256) void pe_step(
    const float2* __restrict__ uv,
    const float*  __restrict__ Tg,
    const float*  __restrict__ qg,
    const float*  __restrict__ psi,
    const float*  __restrict__ quad,
    const float*  __restrict__ f_cor,
    const float*  __restrict__ p_levels,
    const float*  __restrict__ delta_p,
    float* __restrict__ out)
{
  __shared__ float uS[FSH][FSWp], vS[FSH][FSWp], TS[FSH][FSWp], qS[FSH][FSWp];
  __shared__ float keS[FEH][FEWp];
  __shared__ float d1uS[FEH][FEWp], d1vS[FEH][FEWp], d1TS[FEH][FEWp], d1qS[FEH][FEWp];
  __shared__ float P1L[FEH][25];
  __shared__ float P0L[FTH][25];
  __shared__ float quadA[FSH];
  __shared__ float pl[8], dps[8];

  const int tid = threadIdx.x;
  const int tx = tid & (FTW - 1);
  const int ty = tid >> 4;
  const int w0 = blockIdx.x * FTW;
  const int h0 = blockIdx.y * FTH;

  if (tid < FSH) quadA[tid] = quad[clipH(h0 + tid - 4)];
  if (tid < 8) { pl[tid] = p_levels[tid]; dps[tid] = delta_p[tid]; }
  for (int idx = tid; idx < FEH * 25; idx += 256) {
    int ee = idx / 25, t = idx - ee * 25;
    int p = clipH(h0 + ee - 2);
    float s = 0.f;
    #pragma unroll
    for (int kk = 0; kk < 5; ++kk)
      s += psi[kk * (2 * Hh * 25) + Hh * 25 + p * 25 + t];
    P1L[ee][t] = s;
  }
  for (int idx = tid; idx < FTH * 25; idx += 256) {
    int r = idx / 25, t = idx - r * 25;
    int p = clipH(h0 + r);
    float s = 0.f;
    #pragma unroll
    for (int kk = 0; kk < 5; ++kk)
      s += psi[kk * (2 * Hh * 25) + p * 25 + t];
    P0L[r][t] = s;
  }
  __syncthreads();

  const int h = h0 + ty;
  const bool act = h < Hh;
  const int hc = act ? h : (Hh - 1);
  const int w = w0 + tx;
  const float f = f_cor[hc];
  const float invR = (float)(1.0 / 6371000.0);
  const float cL = 200000.0f * invR * invR;
  const float RCP = (float)(287.0 / 1004.0);

  float cum = 0.f;
  float sumT = 0.f;

  #pragma unroll 1
  for (int k = 0; k < Kz; ++k) {
    __syncthreads();
    for (int idx = tid; idx < FSH * FSW; idx += 256) {
      int rr = idx / FSW, cc = idx - rr * FSW;
      int pr = clipH(h0 + rr - 4);
      int pc = w0 + cc - 4;
      pc = pc < 0 ? pc + Ww : (pc >= Ww ? pc - Ww : pc);
      int g = (k * Hh + pr) * Ww + pc;
      float2 uvv = uv[g];
      uS[rr][cc] = uvv.x; vS[rr][cc] = uvv.y;
      TS[rr][cc] = Tg[g]; qS[rr][cc] = qg[g];
    }
    __syncthreads();
    for (int idx = tid; idx < FEH * FEW; idx += 256) {
      int ee = idx / FEW, ec = idx - ee * FEW;
      float su = uS[ee + 2][ec + 2], sv = vS[ee + 2][ec + 2];
      keS[ee][ec] = 0.5f * (su * su + sv * sv);
    }
    for (int idx = tid; idx < FEH * FEW; idx += 256) {
      int ee = idx / FEW, ec = idx - ee * FEW;
      int p = clipH(h0 + ee - 2);
      float au = 0.f, av = 0.f, aT = 0.f, aq = 0.f;
      #pragma unroll
      for (int dl = 0; dl < 5; ++dl) {
        int sp = clipH(p + dl - 2);
        int rr = sp - h0 + 4;
        float qv = quadA[rr];
        float ru = 0.f, rv = 0.f, rT = 0.f, rq = 0.f;
        #pragma unroll
        for (int dw = 0; dw < 5; ++dw) {
          float wgt = P1L[ee][dl * 5 + dw];
          ru = fmaf(wgt, uS[rr][ec + dw], ru);
          rv = fmaf(wgt, vS[rr][ec + dw], rv);
          rT = fmaf(wgt, TS[rr][ec + dw], rT);
          rq = fmaf(wgt, qS[rr][ec + dw], rq);
        }
        au = fmaf(qv, ru, au); av = fmaf(qv, rv, av);
        aT = fmaf(qv, rT, aT); aq = fmaf(qv, rq, aq);
      }
      d1uS[ee][ec] = au; d1vS[ee][ec] = av;
      d1TS[ee][ec] = aT; d1qS[ee][ec] = aq;
    }
    __syncthreads();

    float d0u = 0.f, d1ke = 0.f;
    #pragma unroll
    for (int dl = 0; dl < 5; ++dl) {
      int sp = clipH(hc + dl - 2);
      int rr = sp - h0 + 4;
      int er = sp - h0 + 2;
      float qv = quadA[rr];
      float r0 = 0.f, rk = 0.f;
      #pragma unroll
      for (int dw = 0; dw < 5; ++dw) {
        r0 = fmaf(P0L[ty][dl * 5 + dw], uS[rr][tx + 2 + dw], r0);
        rk = fmaf(P1L[ty + 2][dl * 5 + dw], keS[er][tx + dw], rk);
      }
      d0u = fmaf(qv, r0, d0u);
      d1ke = fmaf(qv, rk, d1ke);
    }

    float lapu = 0.f, lapv = 0.f, lapT = 0.f, lapq = 0.f;
    #pragma unroll
    for (int dl = 0; dl < 5; ++dl) {
      int sp = clipH(hc + dl - 2);
      int er = sp - h0 + 2;
      float qv = quadA[er + 2];
      float ru = 0.f, rv = 0.f, rT = 0.f, rq = 0.f;
      #pragma unroll
      for (int dw = 0; dw < 5; ++dw) {
        float wgt = P1L[ty + 2][dl * 5 + dw];
        ru = fmaf(wgt, d1uS[er][tx + dw], ru);
        rv = fmaf(wgt, d1vS[er][tx + dw], rv);
        rT = fmaf(wgt, d1TS[er][tx + dw], rT);
        rq = fmaf(wgt, d1qS[er][tx + dw], rq);
      }
      lapu = fmaf(qv, ru, lapu); lapv = fmaf(qv, rv, lapv);
      lapT = fmaf(qv, rT, lapT); lapq = fmaf(qv, rq, lapq);
    }

    float d1T_c = d1TS[ty + 2][tx + 2];
    float d1v_c = d1vS[ty + 2][tx + 2];
    float d1q_c = d1qS[ty + 2][tx + 2];
    float uc = uS[ty + 4][tx + 4], vc = vS[ty + 4][tx + 4];
    float Tc = TS[ty + 4][tx + 4];

    float coef1 = fmaf(d0u, invR, -f);
    float duv0 = fmaf(-coef1, vc, cL * lapu);
    float yv1 = fmaf(-invR, d1ke, sumT);
    float duv1 = fmaf(coef1, uc, yv1) + cL * lapv;

    float div = invR * d1v_c;
    float dpk = dps[k];
    float omega = fmaf(0.5f * div, dpk, cum);
    cum = fmaf(div, dpk, cum);

    int gidx = (k * Hh + hc) * Ww + w;
    float dTdp;
    if (k == 0) {
      float Tp = Tg[gidx + HW];
      dTdp = (Tp - Tc) / (pl[1] - pl[0]);
    } else if (k == Kz - 1) {
      float Tm = Tg[gidx - HW];
      dTdp = (Tc - Tm) / (pl[Kz - 1] - pl[Kz - 2]);
    } else {
      float Tp = Tg[gidx + HW];
      float Tm = Tg[gidx - HW];
      dTdp = (Tp - Tm) / (pl[k + 1] - pl[k - 1]);
    }
    float adv = -(invR * d1T_c) * vc;
    float dT = adv + omega * ((RCP * Tc) / pl[k] - dTdp) + cL * lapT;
    float dq = fmaf(-(invR * d1q_c), vc, cL * lapq);

    if (act) {
      ((float2*)out)[(k * Hh + h) * Ww + w] = make_float2(duv0, duv1);
      out[OFF_DT + gidx] = dT;
      out[OFF_DQ + gidx] = dq;
    }

    if (k < Kz - 1) {
      float lpr = logf(pl[k] / pl[k + 1]);
      float wTk = (float)(-287.0 * (double)lpr / 6371000.0);
      sumT = fmaf(wTk, d1T_c, sumT);
    }
  }
}

extern "C" void kernel_launch(void* const* d_in, const int* in_sizes, int n_in,
                              void* d_out, int out_size, void* d_ws, size_t ws_size,
                              hipStream_t stream) {
  (void)in_sizes; (void)n_in; (void)out_size;
  const float2* uv   = (const float2*)d_in[0];
  const float*  T    = (const float*) d_in[1];
  const float*  q    = (const float*) d_in[2];
  const float*  psi  = (const float*) d_in[3];
  const float*  quad = (const float*) d_in[4];
  const float*  fc   = (const float*) d_in[5];
  const float*  pl   = (const float*) d_in[6];
  const float*  dp   = (const float*) d_in[7];

  const size_t ws_div_floats = (size_t)2 * Kz * HW;        // K*HW float2
  const size_t pq_floats = (size_t)Hh * PQROW;             // 14440
  const size_t w2_floats = (size_t)Hh * W2ROW;             // 38988
  const size_t ws_need = (ws_div_floats + 2 * pq_floats + w2_floats) * sizeof(float);
  if (ws_size >= ws_need) {
    float* wsF = (float*)d_ws;
    float* P0g = wsF + ws_div_floats;
    float* P1g = P0g + pq_floats;
    float* W2g = P1g + pq_floats;

    dim3 gt1((Hh * PQROW + 255) / 256);                    // 57 blocks
    hipLaunchKernelGGL(pe_tab_pq, gt1, dim3(256), 0, stream, psi, quad, P0g, P1g);

    dim3 gt2((Hh * 9 + 255) / 256);                        // 13 blocks
    hipLaunchKernelGGL(pe_tab_w2, gt2, dim3(256), 0, stream, P1g, W2g);

    dim3 g1((Ww + TW - 1) / TW, (Hh + TH - 1) / TH, Kz);   // 12 x 23 x 8
    hipLaunchKernelGGL(pe_pass1, g1, dim3(256), 0, stream,
                       uv, T, q, P0g, P1g, W2g, fc, dp, (float*)d_out, (float2*)d_ws);

    dim3 g2((HW / 4 + 255) / 256);
    hipLaunchKernelGGL(pe_pass2, g2, dim3(256), 0, stream,
                       T, pl, (const float2*)d_ws, (float*)d_out);
  } else {
    dim3 grid(Ww / FTW, (Hh + FTH - 1) / FTH);
    hipLaunchKernelGGL(pe_step, grid, dim3(256), 0, stream,
                       uv, T, q, psi, quad, fc, pl, dp, (float*)d_out);
  }
}

// Round 8
// 1283.148 us; speedup vs baseline: 1.6713x; 1.6713x over previous
//
#include <hip/hip_runtime.h>

// Primitive-equations block stepper, gfx950 — R8.
// R7's fused 9x9 double-stencil (Laplacian = D1∘D1 precomputed into W2[h])
// with the spill bug fixed: __launch_bounds__(256,2) instead of (256,4).
// R7's (256,4) capped VGPR at 64 while the fused loop needs ~120 live regs ->
// full scratch spill (FETCH 3.8 GB/dispatch, 2180 us). VGPR cap 256 removes
// the spill; LDS 28 KB still allows multiple blocks/CU.

constexpr int Kz = 8, Hh = 361, Ww = 720;
constexpr int HW = Hh * Ww;              // 259920
constexpr int OFF_DT = Kz * HW * 2;      // 4158720
constexpr int OFF_DQ = OFF_DT + Kz * HW; // 6238080

constexpr int TH = 16, TW = 64;          // outputs per block
constexpr int SH = TH + 8, SW4 = TW + 8; // staged region 24 x 72 points
constexpr int SW4P = 73;                 // S4 row stride (odd mod 8 -> banks)
constexpr int PQROW = 40;                // P-table row stride: 5 a-groups x 8
constexpr int W2ROW = 108;               // W2 row stride: 9 m-groups x 12

__device__ __forceinline__ int clipH(int x) {
  return x < 0 ? 0 : (x > Hh - 1 ? Hh - 1 : x);
}

#define FMA4(acc, s, v)                                                        \
  do {                                                                         \
    acc.x = fmaf((s), (v).x, acc.x);                                           \
    acc.y = fmaf((s), (v).y, acc.y);                                           \
    acc.z = fmaf((s), (v).z, acc.z);                                           \
    acc.w = fmaf((s), (v).w, acc.w);                                           \
  } while (0)

#define LAP9(acc, A, B, C, D, E, F, G, H, I)                                   \
  do {                                                                         \
    FMA4(acc, wa.x, A); FMA4(acc, wa.y, B); FMA4(acc, wa.z, C);                \
    FMA4(acc, wa.w, D); FMA4(acc, wb.x, E); FMA4(acc, wb.y, F);                \
    FMA4(acc, wb.z, G); FMA4(acc, wb.w, H); FMA4(acc, w8, I);                  \
  } while (0)

#define ROW5S(acc, q0, q1, q2, q3, q4, a, b, c, d, e)                          \
  acc = fmaf(q0, a, fmaf(q1, b, fmaf(q2, c, fmaf(q3, d, fmaf(q4, e, acc)))))

// ---------------------------------------------------- P0q/P1q tables --------
__global__ __launch_bounds__(256) void pe_tab_pq(
    const float* __restrict__ psi,
    const float* __restrict__ quad,
    float* __restrict__ P0g,
    float* __restrict__ P1g)
{
  int idx = blockIdx.x * 256 + threadIdx.x;   // h*40 + a*8 + b
  if (idx >= Hh * PQROW) return;
  int h = idx / PQROW, o = idx - h * PQROW;
  int a = o >> 3, b = o & 7;
  float v0 = 0.f, v1 = 0.f;
  if (b < 5) {
    #pragma unroll
    for (int kk = 0; kk < 5; ++kk) {
      v0 += psi[kk * (2 * Hh * 25) + h * 25 + a * 5 + b];
      v1 += psi[kk * (2 * Hh * 25) + Hh * 25 + h * 25 + a * 5 + b];
    }
    float qv = quad[clipH(h + a - 2)];
    v0 *= qv; v1 *= qv;
  }
  P0g[idx] = v0;
  P1g[idx] = v1;
}

// ---------------------------------------------------- W2 9x9 weights --------
__global__ __launch_bounds__(256) void pe_tab_w2(
    const float* __restrict__ P1g,
    float* __restrict__ W2g)
{
  int idx = blockIdx.x * 256 + threadIdx.x;   // h*9 + mi
  if (idx >= Hh * 9) return;
  int h = idx / 9, mi = idx - h * 9;
  int m = mi - 4;
  float n0=0,n1=0,n2=0,n3=0,n4=0,n5=0,n6=0,n7=0,n8=0;
  for (int a = 0; a < 5; ++a) {
    int ra = clipH(h + a - 2);
    float xa0 = P1g[h * PQROW + a * 8 + 0];
    float xa1 = P1g[h * PQROW + a * 8 + 1];
    float xa2 = P1g[h * PQROW + a * 8 + 2];
    float xa3 = P1g[h * PQROW + a * 8 + 3];
    float xa4 = P1g[h * PQROW + a * 8 + 4];
    for (int c = 0; c < 5; ++c) {
      int rc = clipH(ra + c - 2);
      if (rc - h != m) continue;
      float y0 = P1g[ra * PQROW + c * 8 + 0];
      float y1 = P1g[ra * PQROW + c * 8 + 1];
      float y2 = P1g[ra * PQROW + c * 8 + 2];
      float y3 = P1g[ra * PQROW + c * 8 + 3];
      float y4 = P1g[ra * PQROW + c * 8 + 4];
      n0 += xa0*y0;
      n1 += xa0*y1 + xa1*y0;
      n2 += xa0*y2 + xa1*y1 + xa2*y0;
      n3 += xa0*y3 + xa1*y2 + xa2*y1 + xa3*y0;
      n4 += xa0*y4 + xa1*y3 + xa2*y2 + xa3*y1 + xa4*y0;
      n5 += xa1*y4 + xa2*y3 + xa3*y2 + xa4*y1;
      n6 += xa2*y4 + xa3*y3 + xa4*y2;
      n7 += xa3*y4 + xa4*y3;
      n8 += xa4*y4;
    }
  }
  float* w = W2g + h * W2ROW + mi * 12;
  w[0]=n0; w[1]=n1; w[2]=n2; w[3]=n3; w[4]=n4;
  w[5]=n5; w[6]=n6; w[7]=n7; w[8]=n8; w[9]=0.f; w[10]=0.f; w[11]=0.f;
}

// ---------------------------------------------------------------- pass 1 ----
__global__ __launch_bounds__(256, 2) void pe_pass1(
    const float2* __restrict__ uv,
    const float*  __restrict__ Tg,
    const float*  __restrict__ qg,
    const float*  __restrict__ P0g,
    const float*  __restrict__ P1g,
    const float*  __restrict__ W2g,
    const float*  __restrict__ f_cor,
    const float*  __restrict__ delta_p,
    float* __restrict__ out,
    float2* __restrict__ ws)
{
  __shared__ float4 S4[SH][SW4P];       // (u,v,T,q), 28.0 KB — only LDS

  const int tid = threadIdx.x;
  const int tx = tid & 15;              // thread col (owns 4 outputs)
  const int ty = tid >> 4;              // thread row
  const int w0 = blockIdx.x * TW;
  const int h0 = blockIdx.y * TH;
  const int k  = blockIdx.z;

  // ---- stage (u,v,T,q) as float4 with +-4 halo (clip lat, wrap lon) ----
  for (int idx = tid; idx < SH * SW4; idx += 256) {
    int rr = idx / SW4, cc = idx - rr * SW4;
    int pr = clipH(h0 + rr - 4);
    int pc = w0 + cc - 4;
    pc = pc < 0 ? pc + Ww : (pc >= Ww ? pc - Ww : pc);
    int g = (k * Hh + pr) * Ww + pc;
    float2 uvv = uv[g];
    S4[rr][cc] = make_float4(uvv.x, uvv.y, Tg[g], qg[g]);
  }
  __syncthreads();

  const int h = h0 + ty;
  const int hc = h < Hh ? h : (Hh - 1);
  const int wbase = w0 + tx * 4;
  const float f = f_cor[hc];
  const float invR = (float)(1.0 / 6371000.0);
  const float halfInvR = 0.5f * invR;
  const float cL = 200000.0f * invR * invR;
  const float* W2r = W2g + hc * W2ROW;
  const float* P1r = P1g + hc * PQROW;
  const float* P0r = P0g + hc * PQROW;

  float4 lp0 = {0,0,0,0}, lp1 = {0,0,0,0}, lp2 = {0,0,0,0}, lp3 = {0,0,0,0};
  float dvC0=0,dvC1=0,dvC2=0,dvC3=0;   // D1(v) at centers
  float dTC0=0,dTC1=0,dTC2=0,dTC3=0;   // D1(T)
  float dqC0=0,dqC1=0,dqC2=0,dqC3=0;   // D1(q)
  float dk0=0,dk1=0,dk2=0,dk3=0;       // D1(u^2+v^2)
  float du0=0,du1=0,du2=0,du3=0;       // D0(u)
  float2 c0, c1, c2, c3;               // center (u,v)

  #pragma unroll
  for (int m = -4; m <= 4; ++m) {
    int rr = clipH(hc + m) - h0 + 4;
    const float4* srow = &S4[rr][tx * 4];
    float4 s0 = srow[0], s1 = srow[1], s2 = srow[2],  s3 = srow[3];
    float4 s4 = srow[4], s5 = srow[5], s6 = srow[6],  s7 = srow[7];
    float4 s8 = srow[8], s9 = srow[9], s10 = srow[10], s11 = srow[11];

    float4 wa = *(const float4*)(W2r + (m + 4) * 12);
    float4 wb = *(const float4*)(W2r + (m + 4) * 12 + 4);
    float w8 = W2r[(m + 4) * 12 + 8];
    LAP9(lp0, s0, s1, s2, s3, s4, s5, s6, s7, s8);
    LAP9(lp1, s1, s2, s3, s4, s5, s6, s7, s8, s9);
    LAP9(lp2, s2, s3, s4, s5, s6, s7, s8, s9, s10);
    LAP9(lp3, s3, s4, s5, s6, s7, s8, s9, s10, s11);

    if (m >= -2 && m <= 2) {            // compile-time under full unroll
      const int a = m + 2;
      float4 pa = *(const float4*)(P1r + a * 8);
      float p4 = P1r[a * 8 + 4];
      ROW5S(dvC0, pa.x, pa.y, pa.z, pa.w, p4, s2.y, s3.y, s4.y, s5.y, s6.y);
      ROW5S(dvC1, pa.x, pa.y, pa.z, pa.w, p4, s3.y, s4.y, s5.y, s6.y, s7.y);
      ROW5S(dvC2, pa.x, pa.y, pa.z, pa.w, p4, s4.y, s5.y, s6.y, s7.y, s8.y);
      ROW5S(dvC3, pa.x, pa.y, pa.z, pa.w, p4, s5.y, s6.y, s7.y, s8.y, s9.y);
      ROW5S(dTC0, pa.x, pa.y, pa.z, pa.w, p4, s2.z, s3.z, s4.z, s5.z, s6.z);
      ROW5S(dTC1, pa.x, pa.y, pa.z, pa.w, p4, s3.z, s4.z, s5.z, s6.z, s7.z);
      ROW5S(dTC2, pa.x, pa.y, pa.z, pa.w, p4, s4.z, s5.z, s6.z, s7.z, s8.z);
      ROW5S(dTC3, pa.x, pa.y, pa.z, pa.w, p4, s5.z, s6.z, s7.z, s8.z, s9.z);
      ROW5S(dqC0, pa.x, pa.y, pa.z, pa.w, p4, s2.w, s3.w, s4.w, s5.w, s6.w);
      ROW5S(dqC1, pa.x, pa.y, pa.z, pa.w, p4, s3.w, s4.w, s5.w, s6.w, s7.w);
      ROW5S(dqC2, pa.x, pa.y, pa.z, pa.w, p4, s4.w, s5.w, s6.w, s7.w, s8.w);
      ROW5S(dqC3, pa.x, pa.y, pa.z, pa.w, p4, s5.w, s6.w, s7.w, s8.w, s9.w);
      float k2 = fmaf(s2.y, s2.y, s2.x * s2.x);
      float k3 = fmaf(s3.y, s3.y, s3.x * s3.x);
      float k4 = fmaf(s4.y, s4.y, s4.x * s4.x);
      float k5 = fmaf(s5.y, s5.y, s5.x * s5.x);
      float k6 = fmaf(s6.y, s6.y, s6.x * s6.x);
      float k7 = fmaf(s7.y, s7.y, s7.x * s7.x);
      float k8 = fmaf(s8.y, s8.y, s8.x * s8.x);
      float k9 = fmaf(s9.y, s9.y, s9.x * s9.x);
      ROW5S(dk0, pa.x, pa.y, pa.z, pa.w, p4, k2, k3, k4, k5, k6);
      ROW5S(dk1, pa.x, pa.y, pa.z, pa.w, p4, k3, k4, k5, k6, k7);
      ROW5S(dk2, pa.x, pa.y, pa.z, pa.w, p4, k4, k5, k6, k7, k8);
      ROW5S(dk3, pa.x, pa.y, pa.z, pa.w, p4, k5, k6, k7, k8, k9);
      float4 pb = *(const float4*)(P0r + a * 8);
      float pb4 = P0r[a * 8 + 4];
      ROW5S(du0, pb.x, pb.y, pb.z, pb.w, pb4, s2.x, s3.x, s4.x, s5.x, s6.x);
      ROW5S(du1, pb.x, pb.y, pb.z, pb.w, pb4, s3.x, s4.x, s5.x, s6.x, s7.x);
      ROW5S(du2, pb.x, pb.y, pb.z, pb.w, pb4, s4.x, s5.x, s6.x, s7.x, s8.x);
      ROW5S(du3, pb.x, pb.y, pb.z, pb.w, pb4, s5.x, s6.x, s7.x, s8.x, s9.x);
    }
    if (m == 0) {
      c0 = make_float2(s4.x, s4.y);
      c1 = make_float2(s5.x, s5.y);
      c2 = make_float2(s6.x, s6.y);
      c3 = make_float2(s7.x, s7.y);
    }
  }

  if (h < Hh && wbase < Ww) {
    const float dpk = delta_p[k];
    float4 duvA, duvB, dTv, dqv, wsA, wsB;
    {
      float coef1 = fmaf(du0, invR, -f);
      duvA.x = fmaf(-coef1, c0.y, cL * lp0.x);
      duvA.y = fmaf(coef1, c0.x, -halfInvR * dk0) + cL * lp0.y;
      dTv.x = -(invR * dTC0) * c0.y + cL * lp0.z;
      dqv.x = fmaf(-(invR * dqC0), c0.y, cL * lp0.w);
      wsA.x = invR * dvC0 * dpk; wsA.y = dTC0;
    }
    {
      float coef1 = fmaf(du1, invR, -f);
      duvA.z = fmaf(-coef1, c1.y, cL * lp1.x);
      duvA.w = fmaf(coef1, c1.x, -halfInvR * dk1) + cL * lp1.y;
      dTv.y = -(invR * dTC1) * c1.y + cL * lp1.z;
      dqv.y = fmaf(-(invR * dqC1), c1.y, cL * lp1.w);
      wsA.z = invR * dvC1 * dpk; wsA.w = dTC1;
    }
    {
      float coef1 = fmaf(du2, invR, -f);
      duvB.x = fmaf(-coef1, c2.y, cL * lp2.x);
      duvB.y = fmaf(coef1, c2.x, -halfInvR * dk2) + cL * lp2.y;
      dTv.z = -(invR * dTC2) * c2.y + cL * lp2.z;
      dqv.z = fmaf(-(invR * dqC2), c2.y, cL * lp2.w);
      wsB.x = invR * dvC2 * dpk; wsB.y = dTC2;
    }
    {
      float coef1 = fmaf(du3, invR, -f);
      duvB.z = fmaf(-coef1, c3.y, cL * lp3.x);
      duvB.w = fmaf(coef1, c3.x, -halfInvR * dk3) + cL * lp3.y;
      dTv.w = -(invR * dTC3) * c3.y + cL * lp3.z;
      dqv.w = fmaf(-(invR * dqC3), c3.y, cL * lp3.w);
      wsB.z = invR * dvC3 * dpk; wsB.w = dTC3;
    }
    const int gidx = (k * Hh + h) * Ww + wbase;
    float4* o4 = (float4*)out;
    o4[gidx >> 1] = duvA;
    o4[(gidx >> 1) + 1] = duvB;
    *(float4*)&out[OFF_DT + gidx] = dTv;
    *(float4*)&out[OFF_DQ + gidx] = dqv;
    float4* w4 = (float4*)ws;
    w4[gidx >> 1] = wsA;
    w4[(gidx >> 1) + 1] = wsB;
  }
}

// ---------------------------------------------------------------- pass 2 ----
__global__ __launch_bounds__(256) void pe_pass2(
    const float* __restrict__ Tg,
    const float* __restrict__ p_levels,
    const float2* __restrict__ ws,
    float* __restrict__ out)
{
  int i4 = blockIdx.x * 256 + threadIdx.x;   // quad index (4 points/thread)
  if (i4 >= HW / 4) return;
  const float invR = (float)(1.0 / 6371000.0);
  const float RCP = (float)(287.0 / 1004.0);

  float pl[Kz];
  #pragma unroll
  for (int k = 0; k < Kz; ++k) pl[k] = p_levels[k];

  const float4* T4 = (const float4*)Tg;
  const float4* ws4 = (const float4*)ws;
  float4* o4 = (float4*)out;
  float4* dT4 = (float4*)(out + OFF_DT);

  float4 cum = {0,0,0,0}, sumT = {0,0,0,0};
  float4 Tm = {0,0,0,0}, Tc = T4[i4];

  #pragma unroll
  for (int k = 0; k < Kz; ++k) {
    float4 Tp = (k < Kz - 1) ? T4[(k + 1) * (HW / 4) + i4] : make_float4(0,0,0,0);
    float4 wa = ws4[k * (HW / 2) + 2 * i4];
    float4 wb = ws4[k * (HW / 2) + 2 * i4 + 1];
    float om0 = fmaf(0.5f, wa.x, cum.x); cum.x += wa.x;
    float om1 = fmaf(0.5f, wa.z, cum.y); cum.y += wa.z;
    float om2 = fmaf(0.5f, wb.x, cum.z); cum.z += wb.x;
    float om3 = fmaf(0.5f, wb.z, cum.w); cum.w += wb.z;

    float4 dTdp;
    if (k == 0) {
      float idp = 1.f / (pl[1] - pl[0]);
      dTdp.x = (Tp.x - Tc.x) * idp; dTdp.y = (Tp.y - Tc.y) * idp;
      dTdp.z = (Tp.z - Tc.z) * idp; dTdp.w = (Tp.w - Tc.w) * idp;
    } else if (k == Kz - 1) {
      float idp = 1.f / (pl[Kz - 1] - pl[Kz - 2]);
      dTdp.x = (Tc.x - Tm.x) * idp; dTdp.y = (Tc.y - Tm.y) * idp;
      dTdp.z = (Tc.z - Tm.z) * idp; dTdp.w = (Tc.w - Tm.w) * idp;
    } else {
      float idp = 1.f / (pl[k + 1] - pl[k - 1]);
      dTdp.x = (Tp.x - Tm.x) * idp; dTdp.y = (Tp.y - Tm.y) * idp;
      dTdp.z = (Tp.z - Tm.z) * idp; dTdp.w = (Tp.w - Tm.w) * idp;
    }
    float iplk = RCP / pl[k];
    float4 dt = dT4[k * (HW / 4) + i4];
    dt.x += om0 * fmaf(iplk, Tc.x, -dTdp.x);
    dt.y += om1 * fmaf(iplk, Tc.y, -dTdp.y);
    dt.z += om2 * fmaf(iplk, Tc.z, -dTdp.z);
    dt.w += om3 * fmaf(iplk, Tc.w, -dTdp.w);
    dT4[k * (HW / 4) + i4] = dt;

    float4 oa = o4[k * (HW / 2) + 2 * i4];
    float4 ob = o4[k * (HW / 2) + 2 * i4 + 1];
    oa.y += sumT.x; oa.w += sumT.y;
    ob.y += sumT.z; ob.w += sumT.w;
    o4[k * (HW / 2) + 2 * i4] = oa;
    o4[k * (HW / 2) + 2 * i4 + 1] = ob;

    if (k < Kz - 1) {
      float c = -287.0f * logf(pl[k] / pl[k + 1]) * invR;
      sumT.x = fmaf(c, wa.y, sumT.x);
      sumT.y = fmaf(c, wa.w, sumT.y);
      sumT.z = fmaf(c, wb.y, sumT.z);
      sumT.w = fmaf(c, wb.w, sumT.w);
    }
    Tm = Tc; Tc = Tp;
  }
}

// ------------------------------------------------- fallback fused kernel ----
constexpr int FTH = 16, FTW = 16;
constexpr int FSH = FTH + 8, FSW = FTW + 8;
constexpr int FEH = FTH + 4, FEW = FTW + 4;
constexpr int FSWp = FSW + 1, FEWp = FEW + 1;

__global__ __launch_bounds__(256) void pe_step(
    const float2* __restrict__ uv,
    const float*  __restrict__ Tg,
    const float*  __restrict__ qg,
    const float*  __restrict__ psi,
    const float*  __restrict__ quad,
    const float*  __restrict__ f_cor,
    const float*  __restrict__ p_levels,
    const float*  __restrict__ delta_p,
    float* __restrict__ out)
{
  __shared__ float uS[FSH][FSWp], vS[FSH][FSWp], TS[FSH][FSWp], qS[FSH][FSWp];
  __shared__ float keS[FEH][FEWp];
  __shared__ float d1uS[FEH][FEWp], d1vS[FEH][FEWp], d1TS[FEH][FEWp], d1qS[FEH][FEWp];
  __shared__ float P1L[FEH][25];
  __shared__ float P0L[FTH][25];
  __shared__ float quadA[FSH];
  __shared__ float pl[8], dps[8];

  const int tid = threadIdx.x;
  const int tx = tid & (FTW - 1);
  const int ty = tid >> 4;
  const int w0 = blockIdx.x * FTW;
  const int h0 = blockIdx.y * FTH;

  if (tid < FSH) quadA[tid] = quad[clipH(h0 + tid - 4)];
  if (tid < 8) { pl[tid] = p_levels[tid]; dps[tid] = delta_p[tid]; }
  for (int idx = tid; idx < FEH * 25; idx += 256) {
    int ee = idx / 25, t = idx - ee * 25;
    int p = clipH(h0 + ee - 2);
    float s = 0.f;
    #pragma unroll
    for (int kk = 0; kk < 5; ++kk)
      s += psi[kk * (2 * Hh * 25) + Hh * 25 + p * 25 + t];
    P1L[ee][t] = s;
  }
  for (int idx = tid; idx < FTH * 25; idx += 256) {
    int r = idx / 25, t = idx - r * 25;
    int p = clipH(h0 + r);
    float s = 0.f;
    #pragma unroll
    for (int kk = 0; kk < 5; ++kk)
      s += psi[kk * (2 * Hh * 25) + p * 25 + t];
    P0L[r][t] = s;
  }
  __syncthreads();

  const int h = h0 + ty;
  const bool act = h < Hh;
  const int hc = act ? h : (Hh - 1);
  const int w = w0 + tx;
  const float f = f_cor[hc];
  const float invR = (float)(1.0 / 6371000.0);
  const float cL = 200000.0f * invR * invR;
  const float RCP = (float)(287.0 / 1004.0);

  float cum = 0.f;
  float sumT = 0.f;

  #pragma unroll 1
  for (int k = 0; k < Kz; ++k) {
    __syncthreads();
    for (int idx = tid; idx < FSH * FSW; idx += 256) {
      int rr = idx / FSW, cc = idx - rr * FSW;
      int pr = clipH(h0 + rr - 4);
      int pc = w0 + cc - 4;
      pc = pc < 0 ? pc + Ww : (pc >= Ww ? pc - Ww : pc);
      int g = (k * Hh + pr) * Ww + pc;
      float2 uvv = uv[g];
      uS[rr][cc] = uvv.x; vS[rr][cc] = uvv.y;
      TS[rr][cc] = Tg[g]; qS[rr][cc] = qg[g];
    }
    __syncthreads();
    for (int idx = tid; idx < FEH * FEW; idx += 256) {
      int ee = idx / FEW, ec = idx - ee * FEW;
      float su = uS[ee + 2][ec + 2], sv = vS[ee + 2][ec + 2];
      keS[ee][ec] = 0.5f * (su * su + sv * sv);
    }
    for (int idx = tid; idx < FEH * FEW; idx += 256) {
      int ee = idx / FEW, ec = idx - ee * FEW;
      int p = clipH(h0 + ee - 2);
      float au = 0.f, av = 0.f, aT = 0.f, aq = 0.f;
      #pragma unroll
      for (int dl = 0; dl < 5; ++dl) {
        int sp = clipH(p + dl - 2);
        int rr = sp - h0 + 4;
        float qv = quadA[rr];
        float ru = 0.f, rv = 0.f, rT = 0.f, rq = 0.f;
        #pragma unroll
        for (int dw = 0; dw < 5; ++dw) {
          float wgt = P1L[ee][dl * 5 + dw];
          ru = fmaf(wgt, uS[rr][ec + dw], ru);
          rv = fmaf(wgt, vS[rr][ec + dw], rv);
          rT = fmaf(wgt, TS[rr][ec + dw], rT);
          rq = fmaf(wgt, qS[rr][ec + dw], rq);
        }
        au = fmaf(qv, ru, au); av = fmaf(qv, rv, av);
        aT = fmaf(qv, rT, aT); aq = fmaf(qv, rq, aq);
      }
      d1uS[ee][ec] = au; d1vS[ee][ec] = av;
      d1TS[ee][ec] = aT; d1qS[ee][ec] = aq;
    }
    __syncthreads();

    float d0u = 0.f, d1ke = 0.f;
    #pragma unroll
    for (int dl = 0; dl < 5; ++dl) {
      int sp = clipH(hc + dl - 2);
      int rr = sp - h0 + 4;
      int er = sp - h0 + 2;
      float qv = quadA[rr];
      float r0 = 0.f, rk = 0.f;
      #pragma unroll
      for (int dw = 0; dw < 5; ++dw) {
        r0 = fmaf(P0L[ty][dl * 5 + dw], uS[rr][tx + 2 + dw], r0);
        rk = fmaf(P1L[ty + 2][dl * 5 + dw], keS[er][tx + dw], rk);
      }
      d0u = fmaf(qv, r0, d0u);
      d1ke = fmaf(qv, rk, d1ke);
    }

    float lapu = 0.f, lapv = 0.f, lapT = 0.f, lapq = 0.f;
    #pragma unroll
    for (int dl = 0; dl < 5; ++dl) {
      int sp = clipH(hc + dl - 2);
      int er = sp - h0 + 2;
      float qv = quadA[er + 2];
      float ru = 0.f, rv = 0.f, rT = 0.f, rq = 0.f;
      #pragma unroll
      for (int dw = 0; dw < 5; ++dw) {
        float wgt = P1L[ty + 2][dl * 5 + dw];
        ru = fmaf(wgt, d1uS[er][tx + dw], ru);
        rv = fmaf(wgt, d1vS[er][tx + dw], rv);
        rT = fmaf(wgt, d1TS[er][tx + dw], rT);
        rq = fmaf(wgt, d1qS[er][tx + dw], rq);
      }
      lapu = fmaf(qv, ru, lapu); lapv = fmaf(qv, rv, lapv);
      lapT = fmaf(qv, rT, lapT); lapq = fmaf(qv, rq, lapq);
    }

    float d1T_c = d1TS[ty + 2][tx + 2];
    float d1v_c = d1vS[ty + 2][tx + 2];
    float d1q_c = d1qS[ty + 2][tx + 2];
    float uc = uS[ty + 4][tx + 4], vc = vS[ty + 4][tx + 4];
    float Tc = TS[ty + 4][tx + 4];

    float coef1 = fmaf(d0u, invR, -f);
    float duv0 = fmaf(-coef1, vc, cL * lapu);
    float yv1 = fmaf(-invR, d1ke, sumT);
    float duv1 = fmaf(coef1, uc, yv1) + cL * lapv;

    float div = invR * d1v_c;
    float dpk = dps[k];
    float omega = fmaf(0.5f * div, dpk, cum);
    cum = fmaf(div, dpk, cum);

    int gidx = (k * Hh + hc) * Ww + w;
    float dTdp;
    if (k == 0) {
      float Tp = Tg[gidx + HW];
      dTdp = (Tp - Tc) / (pl[1] - pl[0]);
    } else if (k == Kz - 1) {
      float Tm = Tg[gidx - HW];
      dTdp = (Tc - Tm) / (pl[Kz - 1] - pl[Kz - 2]);
    } else {
      float Tp = Tg[gidx + HW];
      float Tm = Tg[gidx - HW];
      dTdp = (Tp - Tm) / (pl[k + 1] - pl[k - 1]);
    }
    float adv = -(invR * d1T_c) * vc;
    float dT = adv + omega * ((RCP * Tc) / pl[k] - dTdp) + cL * lapT;
    float dq = fmaf(-(invR * d1q_c), vc, cL * lapq);

    if (act) {
      ((float2*)out)[(k * Hh + h) * Ww + w] = make_float2(duv0, duv1);
      out[OFF_DT + gidx] = dT;
      out[OFF_DQ + gidx] = dq;
    }

    if (k < Kz - 1) {
      float lpr = logf(pl[k] / pl[k + 1]);
      float wTk = (float)(-287.0 * (double)lpr / 6371000.0);
      sumT = fmaf(wTk, d1T_c, sumT);
    }
  }
}

extern "C" void kernel_launch(void* const* d_in, const int* in_sizes, int n_in,
                              void* d_out, int out_size, void* d_ws, size_t ws_size,
                              hipStream_t stream) {
  (void)in_sizes; (void)n_in; (void)out_size;
  const float2* uv   = (const float2*)d_in[0];
  const float*  T    = (const float*) d_in[1];
  const float*  q    = (const float*) d_in[2];
  const float*  psi  = (const float*) d_in[3];
  const float*  quad = (const float*) d_in[4];
  const float*  fc   = (const float*) d_in[5];
  const float*  pl   = (const float*) d_in[6];
  const float*  dp   = (const float*) d_in[7];

  const size_t ws_div_floats = (size_t)2 * Kz * HW;        // K*HW float2
  const size_t pq_floats = (size_t)Hh * PQROW;             // 14440
  const size_t w2_floats = (size_t)Hh * W2ROW;             // 38988
  const size_t ws_need = (ws_div_floats + 2 * pq_floats + w2_floats) * sizeof(float);
  if (ws_size >= ws_need) {
    float* wsF = (float*)d_ws;
    float* P0g = wsF + ws_div_floats;
    float* P1g = P0g + pq_floats;
    float* W2g = P1g + pq_floats;

    dim3 gt1((Hh * PQROW + 255) / 256);                    // 57 blocks
    hipLaunchKernelGGL(pe_tab_pq, gt1, dim3(256), 0, stream, psi, quad, P0g, P1g);

    dim3 gt2((Hh * 9 + 255) / 256);                        // 13 blocks
    hipLaunchKernelGGL(pe_tab_w2, gt2, dim3(256), 0, stream, P1g, W2g);

    dim3 g1((Ww + TW - 1) / TW, (Hh + TH - 1) / TH, Kz);   // 12 x 23 x 8
    hipLaunchKernelGGL(pe_pass1, g1, dim3(256), 0, stream,
                       uv, T, q, P0g, P1g, W2g, fc, dp, (float*)d_out, (float2*)d_ws);

    dim3 g2((HW / 4 + 255) / 256);
    hipLaunchKernelGGL(pe_pass2, g2, dim3(256), 0, stream,
                       T, pl, (const float2*)d_ws, (float*)d_out);
  } else {
    dim3 grid(Ww / FTW, (Hh + FTH - 1) / FTH);
    hipLaunchKernelGGL(pe_step, grid, dim3(256), 0, stream,
                       uv, T, q, psi, quad, fc, pl, dp, (float*)d_out);
  }
}

// Round 9
// 387.444 us; speedup vs baseline: 5.5351x; 3.3118x over previous
//
#include <hip/hip_runtime.h>

// Primitive-equations block stepper, gfx950 — R9.
// R7/R8 post-mortem: hipcc's VGPR cap for __launch_bounds__(256, k) is
// 256/k (empirical: k=4 -> 64 VGPR, k=2 -> 128 VGPR), and the fused 9x9
// kernel needs ~160 live regs -> both spilled to scratch (GBs of FETCH/WRITE).
// Fix: plain __launch_bounds__(256) — allocator takes ~170 regs, no spill,
// occupancy VGPR-limited at 2-3 waves/SIMD which R6 showed is sufficient.

constexpr int Kz = 8, Hh = 361, Ww = 720;
constexpr int HW = Hh * Ww;              // 259920
constexpr int OFF_DT = Kz * HW * 2;      // 4158720
constexpr int OFF_DQ = OFF_DT + Kz * HW; // 6238080

constexpr int TH = 16, TW = 64;          // outputs per block
constexpr int SH = TH + 8, SW4 = TW + 8; // staged region 24 x 72 points
constexpr int SW4P = 73;                 // S4 row stride (odd mod 8 -> banks)
constexpr int PQROW = 40;                // P-table row stride: 5 a-groups x 8
constexpr int W2ROW = 108;               // W2 row stride: 9 m-groups x 12

__device__ __forceinline__ int clipH(int x) {
  return x < 0 ? 0 : (x > Hh - 1 ? Hh - 1 : x);
}

#define FMA4(acc, s, v)                                                        \
  do {                                                                         \
    acc.x = fmaf((s), (v).x, acc.x);                                           \
    acc.y = fmaf((s), (v).y, acc.y);                                           \
    acc.z = fmaf((s), (v).z, acc.z);                                           \
    acc.w = fmaf((s), (v).w, acc.w);                                           \
  } while (0)

#define LAP9(acc, A, B, C, D, E, F, G, H, I)                                   \
  do {                                                                         \
    FMA4(acc, wa.x, A); FMA4(acc, wa.y, B); FMA4(acc, wa.z, C);                \
    FMA4(acc, wa.w, D); FMA4(acc, wb.x, E); FMA4(acc, wb.y, F);                \
    FMA4(acc, wb.z, G); FMA4(acc, wb.w, H); FMA4(acc, w8, I);                  \
  } while (0)

#define ROW5S(acc, q0, q1, q2, q3, q4, a, b, c, d, e)                          \
  acc = fmaf(q0, a, fmaf(q1, b, fmaf(q2, c, fmaf(q3, d, fmaf(q4, e, acc)))))

// ---------------------------------------------------- P0q/P1q tables --------
__global__ __launch_bounds__(256) void pe_tab_pq(
    const float* __restrict__ psi,
    const float* __restrict__ quad,
    float* __restrict__ P0g,
    float* __restrict__ P1g)
{
  int idx = blockIdx.x * 256 + threadIdx.x;   // h*40 + a*8 + b
  if (idx >= Hh * PQROW) return;
  int h = idx / PQROW, o = idx - h * PQROW;
  int a = o >> 3, b = o & 7;
  float v0 = 0.f, v1 = 0.f;
  if (b < 5) {
    #pragma unroll
    for (int kk = 0; kk < 5; ++kk) {
      v0 += psi[kk * (2 * Hh * 25) + h * 25 + a * 5 + b];
      v1 += psi[kk * (2 * Hh * 25) + Hh * 25 + h * 25 + a * 5 + b];
    }
    float qv = quad[clipH(h + a - 2)];
    v0 *= qv; v1 *= qv;
  }
  P0g[idx] = v0;
  P1g[idx] = v1;
}

// ---------------------------------------------------- W2 9x9 weights --------
__global__ __launch_bounds__(256) void pe_tab_w2(
    const float* __restrict__ P1g,
    float* __restrict__ W2g)
{
  int idx = blockIdx.x * 256 + threadIdx.x;   // h*9 + mi
  if (idx >= Hh * 9) return;
  int h = idx / 9, mi = idx - h * 9;
  int m = mi - 4;
  float n0=0,n1=0,n2=0,n3=0,n4=0,n5=0,n6=0,n7=0,n8=0;
  for (int a = 0; a < 5; ++a) {
    int ra = clipH(h + a - 2);
    float xa0 = P1g[h * PQROW + a * 8 + 0];
    float xa1 = P1g[h * PQROW + a * 8 + 1];
    float xa2 = P1g[h * PQROW + a * 8 + 2];
    float xa3 = P1g[h * PQROW + a * 8 + 3];
    float xa4 = P1g[h * PQROW + a * 8 + 4];
    for (int c = 0; c < 5; ++c) {
      int rc = clipH(ra + c - 2);
      if (rc - h != m) continue;
      float y0 = P1g[ra * PQROW + c * 8 + 0];
      float y1 = P1g[ra * PQROW + c * 8 + 1];
      float y2 = P1g[ra * PQROW + c * 8 + 2];
      float y3 = P1g[ra * PQROW + c * 8 + 3];
      float y4 = P1g[ra * PQROW + c * 8 + 4];
      n0 += xa0*y0;
      n1 += xa0*y1 + xa1*y0;
      n2 += xa0*y2 + xa1*y1 + xa2*y0;
      n3 += xa0*y3 + xa1*y2 + xa2*y1 + xa3*y0;
      n4 += xa0*y4 + xa1*y3 + xa2*y2 + xa3*y1 + xa4*y0;
      n5 += xa1*y4 + xa2*y3 + xa3*y2 + xa4*y1;
      n6 += xa2*y4 + xa3*y3 + xa4*y2;
      n7 += xa3*y4 + xa4*y3;
      n8 += xa4*y4;
    }
  }
  float* w = W2g + h * W2ROW + mi * 12;
  w[0]=n0; w[1]=n1; w[2]=n2; w[3]=n3; w[4]=n4;
  w[5]=n5; w[6]=n6; w[7]=n7; w[8]=n8; w[9]=0.f; w[10]=0.f; w[11]=0.f;
}

// ---------------------------------------------------------------- pass 1 ----
__global__ __launch_bounds__(256) void pe_pass1(
    const float2* __restrict__ uv,
    const float*  __restrict__ Tg,
    const float*  __restrict__ qg,
    const float*  __restrict__ P0g,
    const float*  __restrict__ P1g,
    const float*  __restrict__ W2g,
    const float*  __restrict__ f_cor,
    const float*  __restrict__ delta_p,
    float* __restrict__ out,
    float2* __restrict__ ws)
{
  __shared__ float4 S4[SH][SW4P];       // (u,v,T,q), 28.0 KB — only LDS

  const int tid = threadIdx.x;
  const int tx = tid & 15;              // thread col (owns 4 outputs)
  const int ty = tid >> 4;              // thread row
  const int w0 = blockIdx.x * TW;
  const int h0 = blockIdx.y * TH;
  const int k  = blockIdx.z;

  // ---- stage (u,v,T,q) as float4 with +-4 halo (clip lat, wrap lon) ----
  for (int idx = tid; idx < SH * SW4; idx += 256) {
    int rr = idx / SW4, cc = idx - rr * SW4;
    int pr = clipH(h0 + rr - 4);
    int pc = w0 + cc - 4;
    pc = pc < 0 ? pc + Ww : (pc >= Ww ? pc - Ww : pc);
    int g = (k * Hh + pr) * Ww + pc;
    float2 uvv = uv[g];
    S4[rr][cc] = make_float4(uvv.x, uvv.y, Tg[g], qg[g]);
  }
  __syncthreads();

  const int h = h0 + ty;
  const int hc = h < Hh ? h : (Hh - 1);
  const int wbase = w0 + tx * 4;
  const float f = f_cor[hc];
  const float invR = (float)(1.0 / 6371000.0);
  const float halfInvR = 0.5f * invR;
  const float cL = 200000.0f * invR * invR;
  const float* W2r = W2g + hc * W2ROW;
  const float* P1r = P1g + hc * PQROW;
  const float* P0r = P0g + hc * PQROW;

  float4 lp0 = {0,0,0,0}, lp1 = {0,0,0,0}, lp2 = {0,0,0,0}, lp3 = {0,0,0,0};
  float dvC0=0,dvC1=0,dvC2=0,dvC3=0;   // D1(v) at centers
  float dTC0=0,dTC1=0,dTC2=0,dTC3=0;   // D1(T)
  float dqC0=0,dqC1=0,dqC2=0,dqC3=0;   // D1(q)
  float dk0=0,dk1=0,dk2=0,dk3=0;       // D1(u^2+v^2)
  float du0=0,du1=0,du2=0,du3=0;       // D0(u)
  float2 c0, c1, c2, c3;               // center (u,v)

  #pragma unroll
  for (int m = -4; m <= 4; ++m) {
    int rr = clipH(hc + m) - h0 + 4;
    const float4* srow = &S4[rr][tx * 4];
    float4 s0 = srow[0], s1 = srow[1], s2 = srow[2],  s3 = srow[3];
    float4 s4 = srow[4], s5 = srow[5], s6 = srow[6],  s7 = srow[7];
    float4 s8 = srow[8], s9 = srow[9], s10 = srow[10], s11 = srow[11];

    float4 wa = *(const float4*)(W2r + (m + 4) * 12);
    float4 wb = *(const float4*)(W2r + (m + 4) * 12 + 4);
    float w8 = W2r[(m + 4) * 12 + 8];
    LAP9(lp0, s0, s1, s2, s3, s4, s5, s6, s7, s8);
    LAP9(lp1, s1, s2, s3, s4, s5, s6, s7, s8, s9);
    LAP9(lp2, s2, s3, s4, s5, s6, s7, s8, s9, s10);
    LAP9(lp3, s3, s4, s5, s6, s7, s8, s9, s10, s11);

    if (m >= -2 && m <= 2) {            // compile-time under full unroll
      const int a = m + 2;
      float4 pa = *(const float4*)(P1r + a * 8);
      float p4 = P1r[a * 8 + 4];
      ROW5S(dvC0, pa.x, pa.y, pa.z, pa.w, p4, s2.y, s3.y, s4.y, s5.y, s6.y);
      ROW5S(dvC1, pa.x, pa.y, pa.z, pa.w, p4, s3.y, s4.y, s5.y, s6.y, s7.y);
      ROW5S(dvC2, pa.x, pa.y, pa.z, pa.w, p4, s4.y, s5.y, s6.y, s7.y, s8.y);
      ROW5S(dvC3, pa.x, pa.y, pa.z, pa.w, p4, s5.y, s6.y, s7.y, s8.y, s9.y);
      ROW5S(dTC0, pa.x, pa.y, pa.z, pa.w, p4, s2.z, s3.z, s4.z, s5.z, s6.z);
      ROW5S(dTC1, pa.x, pa.y, pa.z, pa.w, p4, s3.z, s4.z, s5.z, s6.z, s7.z);
      ROW5S(dTC2, pa.x, pa.y, pa.z, pa.w, p4, s4.z, s5.z, s6.z, s7.z, s8.z);
      ROW5S(dTC3, pa.x, pa.y, pa.z, pa.w, p4, s5.z, s6.z, s7.z, s8.z, s9.z);
      ROW5S(dqC0, pa.x, pa.y, pa.z, pa.w, p4, s2.w, s3.w, s4.w, s5.w, s6.w);
      ROW5S(dqC1, pa.x, pa.y, pa.z, pa.w, p4, s3.w, s4.w, s5.w, s6.w, s7.w);
      ROW5S(dqC2, pa.x, pa.y, pa.z, pa.w, p4, s4.w, s5.w, s6.w, s7.w, s8.w);
      ROW5S(dqC3, pa.x, pa.y, pa.z, pa.w, p4, s5.w, s6.w, s7.w, s8.w, s9.w);
      float k2 = fmaf(s2.y, s2.y, s2.x * s2.x);
      float k3 = fmaf(s3.y, s3.y, s3.x * s3.x);
      float k4 = fmaf(s4.y, s4.y, s4.x * s4.x);
      float k5 = fmaf(s5.y, s5.y, s5.x * s5.x);
      float k6 = fmaf(s6.y, s6.y, s6.x * s6.x);
      float k7 = fmaf(s7.y, s7.y, s7.x * s7.x);
      float k8 = fmaf(s8.y, s8.y, s8.x * s8.x);
      float k9 = fmaf(s9.y, s9.y, s9.x * s9.x);
      ROW5S(dk0, pa.x, pa.y, pa.z, pa.w, p4, k2, k3, k4, k5, k6);
      ROW5S(dk1, pa.x, pa.y, pa.z, pa.w, p4, k3, k4, k5, k6, k7);
      ROW5S(dk2, pa.x, pa.y, pa.z, pa.w, p4, k4, k5, k6, k7, k8);
      ROW5S(dk3, pa.x, pa.y, pa.z, pa.w, p4, k5, k6, k7, k8, k9);
      float4 pb = *(const float4*)(P0r + a * 8);
      float pb4 = P0r[a * 8 + 4];
      ROW5S(du0, pb.x, pb.y, pb.z, pb.w, pb4, s2.x, s3.x, s4.x, s5.x, s6.x);
      ROW5S(du1, pb.x, pb.y, pb.z, pb.w, pb4, s3.x, s4.x, s5.x, s6.x, s7.x);
      ROW5S(du2, pb.x, pb.y, pb.z, pb.w, pb4, s4.x, s5.x, s6.x, s7.x, s8.x);
      ROW5S(du3, pb.x, pb.y, pb.z, pb.w, pb4, s5.x, s6.x, s7.x, s8.x, s9.x);
    }
    if (m == 0) {
      c0 = make_float2(s4.x, s4.y);
      c1 = make_float2(s5.x, s5.y);
      c2 = make_float2(s6.x, s6.y);
      c3 = make_float2(s7.x, s7.y);
    }
  }

  if (h < Hh && wbase < Ww) {
    const float dpk = delta_p[k];
    float4 duvA, duvB, dTv, dqv, wsA, wsB;
    {
      float coef1 = fmaf(du0, invR, -f);
      duvA.x = fmaf(-coef1, c0.y, cL * lp0.x);
      duvA.y = fmaf(coef1, c0.x, -halfInvR * dk0) + cL * lp0.y;
      dTv.x = -(invR * dTC0) * c0.y + cL * lp0.z;
      dqv.x = fmaf(-(invR * dqC0), c0.y, cL * lp0.w);
      wsA.x = invR * dvC0 * dpk; wsA.y = dTC0;
    }
    {
      float coef1 = fmaf(du1, invR, -f);
      duvA.z = fmaf(-coef1, c1.y, cL * lp1.x);
      duvA.w = fmaf(coef1, c1.x, -halfInvR * dk1) + cL * lp1.y;
      dTv.y = -(invR * dTC1) * c1.y + cL * lp1.z;
      dqv.y = fmaf(-(invR * dqC1), c1.y, cL * lp1.w);
      wsA.z = invR * dvC1 * dpk; wsA.w = dTC1;
    }
    {
      float coef1 = fmaf(du2, invR, -f);
      duvB.x = fmaf(-coef1, c2.y, cL * lp2.x);
      duvB.y = fmaf(coef1, c2.x, -halfInvR * dk2) + cL * lp2.y;
      dTv.z = -(invR * dTC2) * c2.y + cL * lp2.z;
      dqv.z = fmaf(-(invR * dqC2), c2.y, cL * lp2.w);
      wsB.x = invR * dvC2 * dpk; wsB.y = dTC2;
    }
    {
      float coef1 = fmaf(du3, invR, -f);
      duvB.z = fmaf(-coef1, c3.y, cL * lp3.x);
      duvB.w = fmaf(coef1, c3.x, -halfInvR * dk3) + cL * lp3.y;
      dTv.w = -(invR * dTC3) * c3.y + cL * lp3.z;
      dqv.w = fmaf(-(invR * dqC3), c3.y, cL * lp3.w);
      wsB.z = invR * dvC3 * dpk; wsB.w = dTC3;
    }
    const int gidx = (k * Hh + h) * Ww + wbase;
    float4* o4 = (float4*)out;
    o4[gidx >> 1] = duvA;
    o4[(gidx >> 1) + 1] = duvB;
    *(float4*)&out[OFF_DT + gidx] = dTv;
    *(float4*)&out[OFF_DQ + gidx] = dqv;
    float4* w4 = (float4*)ws;
    w4[gidx >> 1] = wsA;
    w4[(gidx >> 1) + 1] = wsB;
  }
}

// ---------------------------------------------------------------- pass 2 ----
__global__ __launch_bounds__(256) void pe_pass2(
    const float* __restrict__ Tg,
    const float* __restrict__ p_levels,
    const float2* __restrict__ ws,
    float* __restrict__ out)
{
  int i4 = blockIdx.x * 256 + threadIdx.x;   // quad index (4 points/thread)
  if (i4 >= HW / 4) return;
  const float invR = (float)(1.0 / 6371000.0);
  const float RCP = (float)(287.0 / 1004.0);

  float pl[Kz];
  #pragma unroll
  for (int k = 0; k < Kz; ++k) pl[k] = p_levels[k];

  const float4* T4 = (const float4*)Tg;
  const float4* ws4 = (const float4*)ws;
  float4* o4 = (float4*)out;
  float4* dT4 = (float4*)(out + OFF_DT);

  float4 cum = {0,0,0,0}, sumT = {0,0,0,0};
  float4 Tm = {0,0,0,0}, Tc = T4[i4];

  #pragma unroll
  for (int k = 0; k < Kz; ++k) {
    float4 Tp = (k < Kz - 1) ? T4[(k + 1) * (HW / 4) + i4] : make_float4(0,0,0,0);
    float4 wa = ws4[k * (HW / 2) + 2 * i4];
    float4 wb = ws4[k * (HW / 2) + 2 * i4 + 1];
    float om0 = fmaf(0.5f, wa.x, cum.x); cum.x += wa.x;
    float om1 = fmaf(0.5f, wa.z, cum.y); cum.y += wa.z;
    float om2 = fmaf(0.5f, wb.x, cum.z); cum.z += wb.x;
    float om3 = fmaf(0.5f, wb.z, cum.w); cum.w += wb.z;

    float4 dTdp;
    if (k == 0) {
      float idp = 1.f / (pl[1] - pl[0]);
      dTdp.x = (Tp.x - Tc.x) * idp; dTdp.y = (Tp.y - Tc.y) * idp;
      dTdp.z = (Tp.z - Tc.z) * idp; dTdp.w = (Tp.w - Tc.w) * idp;
    } else if (k == Kz - 1) {
      float idp = 1.f / (pl[Kz - 1] - pl[Kz - 2]);
      dTdp.x = (Tc.x - Tm.x) * idp; dTdp.y = (Tc.y - Tm.y) * idp;
      dTdp.z = (Tc.z - Tm.z) * idp; dTdp.w = (Tc.w - Tm.w) * idp;
    } else {
      float idp = 1.f / (pl[k + 1] - pl[k - 1]);
      dTdp.x = (Tp.x - Tm.x) * idp; dTdp.y = (Tp.y - Tm.y) * idp;
      dTdp.z = (Tp.z - Tm.z) * idp; dTdp.w = (Tp.w - Tm.w) * idp;
    }
    float iplk = RCP / pl[k];
    float4 dt = dT4[k * (HW / 4) + i4];
    dt.x += om0 * fmaf(iplk, Tc.x, -dTdp.x);
    dt.y += om1 * fmaf(iplk, Tc.y, -dTdp.y);
    dt.z += om2 * fmaf(iplk, Tc.z, -dTdp.z);
    dt.w += om3 * fmaf(iplk, Tc.w, -dTdp.w);
    dT4[k * (HW / 4) + i4] = dt;

    float4 oa = o4[k * (HW / 2) + 2 * i4];
    float4 ob = o4[k * (HW / 2) + 2 * i4 + 1];
    oa.y += sumT.x; oa.w += sumT.y;
    ob.y += sumT.z; ob.w += sumT.w;
    o4[k * (HW / 2) + 2 * i4] = oa;
    o4[k * (HW / 2) + 2 * i4 + 1] = ob;

    if (k < Kz - 1) {
      float c = -287.0f * logf(pl[k] / pl[k + 1]) * invR;
      sumT.x = fmaf(c, wa.y, sumT.x);
      sumT.y = fmaf(c, wa.w, sumT.y);
      sumT.z = fmaf(c, wb.y, sumT.z);
      sumT.w = fmaf(c, wb.w, sumT.w);
    }
    Tm = Tc; Tc = Tp;
  }
}

// ------------------------------------------------- fallback fused kernel ----
constexpr int FTH = 16, FTW = 16;
constexpr int FSH = FTH + 8, FSW = FTW + 8;
constexpr int FEH = FTH + 4, FEW = FTW + 4;
constexpr int FSWp = FSW + 1, FEWp = FEW + 1;

__global__ __launch_bounds__(256) void pe_step(
    const float2* __restrict__ uv,
    const float*  __restrict__ Tg,
    const float*  __restrict__ qg,
    const float*  __restrict__ psi,
    const float*  __restrict__ quad,
    const float*  __restrict__ f_cor,
    const float*  __restrict__ p_levels,
    const float*  __restrict__ delta_p,
    float* __restrict__ out)
{
  __shared__ float uS[FSH][FSWp], vS[FSH][FSWp], TS[FSH][FSWp], qS[FSH][FSWp];
  __shared__ float keS[FEH][FEWp];
  __shared__ float d1uS[FEH][FEWp], d1vS[FEH][FEWp], d1TS[FEH][FEWp], d1qS[FEH][FEWp];
  __shared__ float P1L[FEH][25];
  __shared__ float P0L[FTH][25];
  __shared__ float quadA[FSH];
  __shared__ float pl[8], dps[8];

  const int tid = threadIdx.x;
  const int tx = tid & (FTW - 1);
  const int ty = tid >> 4;
  const int w0 = blockIdx.x * FTW;
  const int h0 = blockIdx.y * FTH;

  if (tid < FSH) quadA[tid] = quad[clipH(h0 + tid - 4)];
  if (tid < 8) { pl[tid] = p_levels[tid]; dps[tid] = delta_p[tid]; }
  for (int idx = tid; idx < FEH * 25; idx += 256) {
    int ee = idx / 25, t = idx - ee * 25;
    int p = clipH(h0 + ee - 2);
    float s = 0.f;
    #pragma unroll
    for (int kk = 0; kk < 5; ++kk)
      s += psi[kk * (2 * Hh * 25) + Hh * 25 + p * 25 + t];
    P1L[ee][t] = s;
  }
  for (int idx = tid; idx < FTH * 25; idx += 256) {
    int r = idx / 25, t = idx - r * 25;
    int p = clipH(h0 + r);
    float s = 0.f;
    #pragma unroll
    for (int kk = 0; kk < 5; ++kk)
      s += psi[kk * (2 * Hh * 25) + p * 25 + t];
    P0L[r][t] = s;
  }
  __syncthreads();

  const int h = h0 + ty;
  const bool act = h < Hh;
  const int hc = act ? h : (Hh - 1);
  const int w = w0 + tx;
  const float f = f_cor[hc];
  const float invR = (float)(1.0 / 6371000.0);
  const float cL = 200000.0f * invR * invR;
  const float RCP = (float)(287.0 / 1004.0);

  float cum = 0.f;
  float sumT = 0.f;

  #pragma unroll 1
  for (int k = 0; k < Kz; ++k) {
    __syncthreads();
    for (int idx = tid; idx < FSH * FSW; idx += 256) {
      int rr = idx / FSW, cc = idx - rr * FSW;
      int pr = clipH(h0 + rr - 4);
      int pc = w0 + cc - 4;
      pc = pc < 0 ? pc + Ww : (pc >= Ww ? pc - Ww : pc);
      int g = (k * Hh + pr) * Ww + pc;
      float2 uvv = uv[g];
      uS[rr][cc] = uvv.x; vS[rr][cc] = uvv.y;
      TS[rr][cc] = Tg[g]; qS[rr][cc] = qg[g];
    }
    __syncthreads();
    for (int idx = tid; idx < FEH * FEW; idx += 256) {
      int ee = idx / FEW, ec = idx - ee * FEW;
      float su = uS[ee + 2][ec + 2], sv = vS[ee + 2][ec + 2];
      keS[ee][ec] = 0.5f * (su * su + sv * sv);
    }
    for (int idx = tid; idx < FEH * FEW; idx += 256) {
      int ee = idx / FEW, ec = idx - ee * FEW;
      int p = clipH(h0 + ee - 2);
      float au = 0.f, av = 0.f, aT = 0.f, aq = 0.f;
      #pragma unroll
      for (int dl = 0; dl < 5; ++dl) {
        int sp = clipH(p + dl - 2);
        int rr = sp - h0 + 4;
        float qv = quadA[rr];
        float ru = 0.f, rv = 0.f, rT = 0.f, rq = 0.f;
        #pragma unroll
        for (int dw = 0; dw < 5; ++dw) {
          float wgt = P1L[ee][dl * 5 + dw];
          ru = fmaf(wgt, uS[rr][ec + dw], ru);
          rv = fmaf(wgt, vS[rr][ec + dw], rv);
          rT = fmaf(wgt, TS[rr][ec + dw], rT);
          rq = fmaf(wgt, qS[rr][ec + dw], rq);
        }
        au = fmaf(qv, ru, au); av = fmaf(qv, rv, av);
        aT = fmaf(qv, rT, aT); aq = fmaf(qv, rq, aq);
      }
      d1uS[ee][ec] = au; d1vS[ee][ec] = av;
      d1TS[ee][ec] = aT; d1qS[ee][ec] = aq;
    }
    __syncthreads();

    float d0u = 0.f, d1ke = 0.f;
    #pragma unroll
    for (int dl = 0; dl < 5; ++dl) {
      int sp = clipH(hc + dl - 2);
      int rr = sp - h0 + 4;
      int er = sp - h0 + 2;
      float qv = quadA[rr];
      float r0 = 0.f, rk = 0.f;
      #pragma unroll
      for (int dw = 0; dw < 5; ++dw) {
        r0 = fmaf(P0L[ty][dl * 5 + dw], uS[rr][tx + 2 + dw], r0);
        rk = fmaf(P1L[ty + 2][dl * 5 + dw], keS[er][tx + dw], rk);
      }
      d0u = fmaf(qv, r0, d0u);
      d1ke = fmaf(qv, rk, d1ke);
    }

    float lapu = 0.f, lapv = 0.f, lapT = 0.f, lapq = 0.f;
    #pragma unroll
    for (int dl = 0; dl < 5; ++dl) {
      int sp = clipH(hc + dl - 2);
      int er = sp - h0 + 2;
      float qv = quadA[er + 2];
      float ru = 0.f, rv = 0.f, rT = 0.f, rq = 0.f;
      #pragma unroll
      for (int dw = 0; dw < 5; ++dw) {
        float wgt = P1L[ty + 2][dl * 5 + dw];
        ru = fmaf(wgt, d1uS[er][tx + dw], ru);
        rv = fmaf(wgt, d1vS[er][tx + dw], rv);
        rT = fmaf(wgt, d1TS[er][tx + dw], rT);
        rq = fmaf(wgt, d1qS[er][tx + dw], rq);
      }
      lapu = fmaf(qv, ru, lapu); lapv = fmaf(qv, rv, lapv);
      lapT = fmaf(qv, rT, lapT); lapq = fmaf(qv, rq, lapq);
    }

    float d1T_c = d1TS[ty + 2][tx + 2];
    float d1v_c = d1vS[ty + 2][tx + 2];
    float d1q_c = d1qS[ty + 2][tx + 2];
    float uc = uS[ty + 4][tx + 4], vc = vS[ty + 4][tx + 4];
    float Tc = TS[ty + 4][tx + 4];

    float coef1 = fmaf(d0u, invR, -f);
    float duv0 = fmaf(-coef1, vc, cL * lapu);
    float yv1 = fmaf(-invR, d1ke, sumT);
    float duv1 = fmaf(coef1, uc, yv1) + cL * lapv;

    float div = invR * d1v_c;
    float dpk = dps[k];
    float omega = fmaf(0.5f * div, dpk, cum);
    cum = fmaf(div, dpk, cum);

    int gidx = (k * Hh + hc) * Ww + w;
    float dTdp;
    if (k == 0) {
      float Tp = Tg[gidx + HW];
      dTdp = (Tp - Tc) / (pl[1] - pl[0]);
    } else if (k == Kz - 1) {
      float Tm = Tg[gidx - HW];
      dTdp = (Tc - Tm) / (pl[Kz - 1] - pl[Kz - 2]);
    } else {
      float Tp = Tg[gidx + HW];
      float Tm = Tg[gidx - HW];
      dTdp = (Tp - Tm) / (pl[k + 1] - pl[k - 1]);
    }
    float adv = -(invR * d1T_c) * vc;
    float dT = adv + omega * ((RCP * Tc) / pl[k] - dTdp) + cL * lapT;
    float dq = fmaf(-(invR * d1q_c), vc, cL * lapq);

    if (act) {
      ((float2*)out)[(k * Hh + h) * Ww + w] = make_float2(duv0, duv1);
      out[OFF_DT + gidx] = dT;
      out[OFF_DQ + gidx] = dq;
    }

    if (k < Kz - 1) {
      float lpr = logf(pl[k] / pl[k + 1]);
      float wTk = (float)(-287.0 * (double)lpr / 6371000.0);
      sumT = fmaf(wTk, d1T_c, sumT);
    }
  }
}

extern "C" void kernel_launch(void* const* d_in, const int* in_sizes, int n_in,
                              void* d_out, int out_size, void* d_ws, size_t ws_size,
                              hipStream_t stream) {
  (void)in_sizes; (void)n_in; (void)out_size;
  const float2* uv   = (const float2*)d_in[0];
  const float*  T    = (const float*) d_in[1];
  const float*  q    = (const float*) d_in[2];
  const float*  psi  = (const float*) d_in[3];
  const float*  quad = (const float*) d_in[4];
  const float*  fc   = (const float*) d_in[5];
  const float*  pl   = (const float*) d_in[6];
  const float*  dp   = (const float*) d_in[7];

  const size_t ws_div_floats = (size_t)2 * Kz * HW;        // K*HW float2
  const size_t pq_floats = (size_t)Hh * PQROW;             // 14440
  const size_t w2_floats = (size_t)Hh * W2ROW;             // 38988
  const size_t ws_need = (ws_div_floats + 2 * pq_floats + w2_floats) * sizeof(float);
  if (ws_size >= ws_need) {
    float* wsF = (float*)d_ws;
    float* P0g = wsF + ws_div_floats;
    float* P1g = P0g + pq_floats;
    float* W2g = P1g + pq_floats;

    dim3 gt1((Hh * PQROW + 255) / 256);                    // 57 blocks
    hipLaunchKernelGGL(pe_tab_pq, gt1, dim3(256), 0, stream, psi, quad, P0g, P1g);

    dim3 gt2((Hh * 9 + 255) / 256);                        // 13 blocks
    hipLaunchKernelGGL(pe_tab_w2, gt2, dim3(256), 0, stream, P1g, W2g);

    dim3 g1((Ww + TW - 1) / TW, (Hh + TH - 1) / TH, Kz);   // 12 x 23 x 8
    hipLaunchKernelGGL(pe_pass1, g1, dim3(256), 0, stream,
                       uv, T, q, P0g, P1g, W2g, fc, dp, (float*)d_out, (float2*)d_ws);

    dim3 g2((HW / 4 + 255) / 256);
    hipLaunchKernelGGL(pe_pass2, g2, dim3(256), 0, stream,
                       T, pl, (const float2*)d_ws, (float*)d_out);
  } else {
    dim3 grid(Ww / FTW, (Hh + FTH - 1) / FTH);
    hipLaunchKernelGGL(pe_step, grid, dim3(256), 0, stream,
                       uv, T, q, psi, quad, fc, pl, dp, (float*)d_out);
  }
}

// Round 10
// 91.356 us; speedup vs baseline: 23.4745x; 4.2410x over previous
//
#include <hip/hip_runtime.h>

// Primitive-equations block stepper, gfx950 — R10.
// 9x9 fused double-stencil (W2 = D1∘D1 table) with the register-pressure fix:
// LDS de-interleaved into planes (uv float2-plane, T, q scalar planes) and the
// 9-row loop split into per-field ROLLED phases (#pragma unroll 1). Each phase
// holds only a 12-24 float window + accumulators -> ~130 live VGPRs, no spill
// (R7-R9 packed-float4 fused kernel needed >256 -> GBs of scratch traffic).

constexpr int Kz = 8, Hh = 361, Ww = 720;
constexpr int HW = Hh * Ww;              // 259920
constexpr int OFF_DT = Kz * HW * 2;      // 4158720
constexpr int OFF_DQ = OFF_DT + Kz * HW; // 6238080

constexpr int TH = 16, TW = 64;          // outputs per block
constexpr int SH = TH + 8, SW4 = TW + 8; // staged region 24 x 72 points
constexpr int UVROW = 148;               // uv plane row stride (floats): 37 f4, odd mod 8
constexpr int TROW  = 76;                // T/q plane row stride (floats): 19 f4, odd mod 8
constexpr int PQROW = 40;                // P-table row stride: 5 a-groups x 8
constexpr int W2ROW = 108;               // W2 row stride: 9 m-groups x 12

__device__ __forceinline__ int clipH(int x) {
  return x < 0 ? 0 : (x > Hh - 1 ? Hh - 1 : x);
}

// ---------------------------------------------------- P0q/P1q tables --------
__global__ __launch_bounds__(256) void pe_tab_pq(
    const float* __restrict__ psi,
    const float* __restrict__ quad,
    float* __restrict__ P0g,
    float* __restrict__ P1g)
{
  int idx = blockIdx.x * 256 + threadIdx.x;   // h*40 + a*8 + b
  if (idx >= Hh * PQROW) return;
  int h = idx / PQROW, o = idx - h * PQROW;
  int a = o >> 3, b = o & 7;
  float v0 = 0.f, v1 = 0.f;
  if (b < 5) {
    #pragma unroll
    for (int kk = 0; kk < 5; ++kk) {
      v0 += psi[kk * (2 * Hh * 25) + h * 25 + a * 5 + b];
      v1 += psi[kk * (2 * Hh * 25) + Hh * 25 + h * 25 + a * 5 + b];
    }
    float qv = quad[clipH(h + a - 2)];
    v0 *= qv; v1 *= qv;
  }
  P0g[idx] = v0;
  P1g[idx] = v1;
}

// ---------------------------------------------------- W2 9x9 weights --------
__global__ __launch_bounds__(256) void pe_tab_w2(
    const float* __restrict__ P1g,
    float* __restrict__ W2g)
{
  int idx = blockIdx.x * 256 + threadIdx.x;   // h*9 + mi
  if (idx >= Hh * 9) return;
  int h = idx / 9, mi = idx - h * 9;
  int m = mi - 4;
  float n0=0,n1=0,n2=0,n3=0,n4=0,n5=0,n6=0,n7=0,n8=0;
  for (int a = 0; a < 5; ++a) {
    int ra = clipH(h + a - 2);
    float xa0 = P1g[h * PQROW + a * 8 + 0];
    float xa1 = P1g[h * PQROW + a * 8 + 1];
    float xa2 = P1g[h * PQROW + a * 8 + 2];
    float xa3 = P1g[h * PQROW + a * 8 + 3];
    float xa4 = P1g[h * PQROW + a * 8 + 4];
    for (int c = 0; c < 5; ++c) {
      int rc = clipH(ra + c - 2);
      if (rc - h != m) continue;
      float y0 = P1g[ra * PQROW + c * 8 + 0];
      float y1 = P1g[ra * PQROW + c * 8 + 1];
      float y2 = P1g[ra * PQROW + c * 8 + 2];
      float y3 = P1g[ra * PQROW + c * 8 + 3];
      float y4 = P1g[ra * PQROW + c * 8 + 4];
      n0 += xa0*y0;
      n1 += xa0*y1 + xa1*y0;
      n2 += xa0*y2 + xa1*y1 + xa2*y0;
      n3 += xa0*y3 + xa1*y2 + xa2*y1 + xa3*y0;
      n4 += xa0*y4 + xa1*y3 + xa2*y2 + xa3*y1 + xa4*y0;
      n5 += xa1*y4 + xa2*y3 + xa3*y2 + xa4*y1;
      n6 += xa2*y4 + xa3*y3 + xa4*y2;
      n7 += xa3*y4 + xa4*y3;
      n8 += xa4*y4;
    }
  }
  float* w = W2g + h * W2ROW + mi * 12;
  w[0]=n0; w[1]=n1; w[2]=n2; w[3]=n3; w[4]=n4;
  w[5]=n5; w[6]=n6; w[7]=n7; w[8]=n8; w[9]=0.f; w[10]=0.f; w[11]=0.f;
}

// ---------------------------------------------------------------- pass 1 ----
__global__ __launch_bounds__(256) void pe_pass1(
    const float2* __restrict__ uv,
    const float*  __restrict__ Tg,
    const float*  __restrict__ qg,
    const float*  __restrict__ P0g,
    const float*  __restrict__ P1g,
    const float*  __restrict__ W2g,
    const float*  __restrict__ f_cor,
    const float*  __restrict__ delta_p,
    float* __restrict__ out,
    float2* __restrict__ ws)
{
  __shared__ __align__(16) float uvS[SH * UVROW];  // 14.2 KB
  __shared__ __align__(16) float TSl[SH * TROW];   //  7.3 KB
  __shared__ __align__(16) float qSl[SH * TROW];   //  7.3 KB

  const int tid = threadIdx.x;
  const int tx = tid & 15;              // thread col (owns 4 outputs)
  const int ty = tid >> 4;              // thread row
  const int w0 = blockIdx.x * TW;
  const int h0 = blockIdx.y * TH;
  const int k  = blockIdx.z;

  // ---- stage planes with +-4 halo (clip lat, wrap lon) ----
  for (int idx = tid; idx < SH * SW4; idx += 256) {
    int rr = idx / SW4, cc = idx - rr * SW4;
    int pr = clipH(h0 + rr - 4);
    int pc = w0 + cc - 4;
    pc = pc < 0 ? pc + Ww : (pc >= Ww ? pc - Ww : pc);
    int g = (k * Hh + pr) * Ww + pc;
    *(float2*)&uvS[rr * UVROW + 2 * cc] = uv[g];
    TSl[rr * TROW + cc] = Tg[g];
    qSl[rr * TROW + cc] = qg[g];
  }
  __syncthreads();

  const int h = h0 + ty;
  const int hc = h < Hh ? h : (Hh - 1);
  const int wbase = w0 + tx * 4;
  const float f = f_cor[hc];
  const float invR = (float)(1.0 / 6371000.0);
  const float halfInvR = 0.5f * invR;
  const float cL = 200000.0f * invR * invR;
  const float* W2r = W2g + hc * W2ROW;
  const float* P1r = P1g + hc * PQROW;
  const float* P0r = P0g + hc * PQROW;

  float lpu[4] = {0,0,0,0}, lpv[4] = {0,0,0,0};
  float dvC[4] = {0,0,0,0}, dkk[4] = {0,0,0,0}, duu[4] = {0,0,0,0};
  float ucn[4], vcn[4];

  // ---------- phase 1: uv plane (lap u, lap v, D1 v, D1 ke, D0 u) ----------
  #pragma unroll 1
  for (int m = -4; m <= 4; ++m) {
    int rr = clipH(hc + m) - h0 + 4;
    const float4* row = (const float4*)&uvS[rr * UVROW + tx * 8];
    float4 g0 = row[0], g1 = row[1], g2 = row[2];
    float4 g3 = row[3], g4 = row[4], g5 = row[5];
    float uu[12] = {g0.x,g0.z,g1.x,g1.z,g2.x,g2.z,g3.x,g3.z,g4.x,g4.z,g5.x,g5.z};
    float vv[12] = {g0.y,g0.w,g1.y,g1.w,g2.y,g2.w,g3.y,g3.w,g4.y,g4.w,g5.y,g5.w};

    float wn[9];
    *(float4*)&wn[0] = *(const float4*)(W2r + (m + 4) * 12);
    *(float4*)&wn[4] = *(const float4*)(W2r + (m + 4) * 12 + 4);
    wn[8] = W2r[(m + 4) * 12 + 8];
    #pragma unroll
    for (int n = 0; n < 9; ++n) {
      float wgt = wn[n];
      #pragma unroll
      for (int j = 0; j < 4; ++j) {
        lpu[j] = fmaf(wgt, uu[n + j], lpu[j]);
        lpv[j] = fmaf(wgt, vv[n + j], lpv[j]);
      }
    }
    if (m >= -2 && m <= 2) {
      float p1[5], p0[5];
      *(float4*)&p1[0] = *(const float4*)(P1r + (m + 2) * 8);
      p1[4] = P1r[(m + 2) * 8 + 4];
      *(float4*)&p0[0] = *(const float4*)(P0r + (m + 2) * 8);
      p0[4] = P0r[(m + 2) * 8 + 4];
      float ka[12];
      #pragma unroll
      for (int i = 2; i < 11; ++i)
        ka[i] = fmaf(uu[i], uu[i], vv[i] * vv[i]);
      #pragma unroll
      for (int n = 0; n < 5; ++n) {
        float w1 = p1[n], w0_ = p0[n];
        #pragma unroll
        for (int j = 0; j < 4; ++j) {
          dvC[j] = fmaf(w1, vv[n + 2 + j], dvC[j]);
          dkk[j] = fmaf(w1, ka[n + 2 + j], dkk[j]);
          duu[j] = fmaf(w0_, uu[n + 2 + j], duu[j]);
        }
      }
    }
    if (m == 0) {
      #pragma unroll
      for (int j = 0; j < 4; ++j) { ucn[j] = uu[4 + j]; vcn[j] = vv[4 + j]; }
    }
  }

  // ---------- phase 2: T plane (lap T, D1 T) ----------
  float lpT[4] = {0,0,0,0}, dTC[4] = {0,0,0,0};
  #pragma unroll 1
  for (int m = -4; m <= 4; ++m) {
    int rr = clipH(hc + m) - h0 + 4;
    const float4* row = (const float4*)&TSl[rr * TROW + tx * 4];
    float4 a = row[0], b = row[1], c = row[2];
    float tt[12] = {a.x,a.y,a.z,a.w,b.x,b.y,b.z,b.w,c.x,c.y,c.z,c.w};
    float wn[9];
    *(float4*)&wn[0] = *(const float4*)(W2r + (m + 4) * 12);
    *(float4*)&wn[4] = *(const float4*)(W2r + (m + 4) * 12 + 4);
    wn[8] = W2r[(m + 4) * 12 + 8];
    #pragma unroll
    for (int n = 0; n < 9; ++n) {
      float wgt = wn[n];
      #pragma unroll
      for (int j = 0; j < 4; ++j)
        lpT[j] = fmaf(wgt, tt[n + j], lpT[j]);
    }
    if (m >= -2 && m <= 2) {
      float p1[5];
      *(float4*)&p1[0] = *(const float4*)(P1r + (m + 2) * 8);
      p1[4] = P1r[(m + 2) * 8 + 4];
      #pragma unroll
      for (int n = 0; n < 5; ++n) {
        float w1 = p1[n];
        #pragma unroll
        for (int j = 0; j < 4; ++j)
          dTC[j] = fmaf(w1, tt[n + 2 + j], dTC[j]);
      }
    }
  }

  // ---------- phase 3: q plane (lap q, D1 q) ----------
  float lpq[4] = {0,0,0,0}, dqC[4] = {0,0,0,0};
  #pragma unroll 1
  for (int m = -4; m <= 4; ++m) {
    int rr = clipH(hc + m) - h0 + 4;
    const float4* row = (const float4*)&qSl[rr * TROW + tx * 4];
    float4 a = row[0], b = row[1], c = row[2];
    float tt[12] = {a.x,a.y,a.z,a.w,b.x,b.y,b.z,b.w,c.x,c.y,c.z,c.w};
    float wn[9];
    *(float4*)&wn[0] = *(const float4*)(W2r + (m + 4) * 12);
    *(float4*)&wn[4] = *(const float4*)(W2r + (m + 4) * 12 + 4);
    wn[8] = W2r[(m + 4) * 12 + 8];
    #pragma unroll
    for (int n = 0; n < 9; ++n) {
      float wgt = wn[n];
      #pragma unroll
      for (int j = 0; j < 4; ++j)
        lpq[j] = fmaf(wgt, tt[n + j], lpq[j]);
    }
    if (m >= -2 && m <= 2) {
      float p1[5];
      *(float4*)&p1[0] = *(const float4*)(P1r + (m + 2) * 8);
      p1[4] = P1r[(m + 2) * 8 + 4];
      #pragma unroll
      for (int n = 0; n < 5; ++n) {
        float w1 = p1[n];
        #pragma unroll
        for (int j = 0; j < 4; ++j)
          dqC[j] = fmaf(w1, tt[n + 2 + j], dqC[j]);
      }
    }
  }

  // ---------- pointwise + store ----------
  if (h < Hh && wbase < Ww) {
    const float dpk = delta_p[k];
    float duv0[4], duv1[4], dTo[4], dqo[4], wsx[4], wsy[4];
    #pragma unroll
    for (int j = 0; j < 4; ++j) {
      float coef1 = fmaf(duu[j], invR, -f);
      duv0[j] = fmaf(-coef1, vcn[j], cL * lpu[j]);
      duv1[j] = fmaf(coef1, ucn[j], -halfInvR * dkk[j]) + cL * lpv[j];
      dTo[j] = -(invR * dTC[j]) * vcn[j] + cL * lpT[j];
      dqo[j] = fmaf(-(invR * dqC[j]), vcn[j], cL * lpq[j]);
      wsx[j] = invR * dvC[j] * dpk;
      wsy[j] = dTC[j];
    }
    const int gidx = (k * Hh + h) * Ww + wbase;
    float4* o4 = (float4*)out;
    o4[gidx >> 1] = make_float4(duv0[0], duv1[0], duv0[1], duv1[1]);
    o4[(gidx >> 1) + 1] = make_float4(duv0[2], duv1[2], duv0[3], duv1[3]);
    *(float4*)&out[OFF_DT + gidx] = make_float4(dTo[0], dTo[1], dTo[2], dTo[3]);
    *(float4*)&out[OFF_DQ + gidx] = make_float4(dqo[0], dqo[1], dqo[2], dqo[3]);
    float4* w4 = (float4*)ws;
    w4[gidx >> 1] = make_float4(wsx[0], wsy[0], wsx[1], wsy[1]);
    w4[(gidx >> 1) + 1] = make_float4(wsx[2], wsy[2], wsx[3], wsy[3]);
  }
}

// ---------------------------------------------------------------- pass 2 ----
__global__ __launch_bounds__(256) void pe_pass2(
    const float* __restrict__ Tg,
    const float* __restrict__ p_levels,
    const float2* __restrict__ ws,
    float* __restrict__ out)
{
  int i4 = blockIdx.x * 256 + threadIdx.x;   // quad index (4 points/thread)
  if (i4 >= HW / 4) return;
  const float invR = (float)(1.0 / 6371000.0);
  const float RCP = (float)(287.0 / 1004.0);

  float pl[Kz];
  #pragma unroll
  for (int k = 0; k < Kz; ++k) pl[k] = p_levels[k];

  const float4* T4 = (const float4*)Tg;
  const float4* ws4 = (const float4*)ws;
  float4* o4 = (float4*)out;
  float4* dT4 = (float4*)(out + OFF_DT);

  float4 cum = {0,0,0,0}, sumT = {0,0,0,0};
  float4 Tm = {0,0,0,0}, Tc = T4[i4];

  #pragma unroll
  for (int k = 0; k < Kz; ++k) {
    float4 Tp = (k < Kz - 1) ? T4[(k + 1) * (HW / 4) + i4] : make_float4(0,0,0,0);
    float4 wa = ws4[k * (HW / 2) + 2 * i4];
    float4 wb = ws4[k * (HW / 2) + 2 * i4 + 1];
    float om0 = fmaf(0.5f, wa.x, cum.x); cum.x += wa.x;
    float om1 = fmaf(0.5f, wa.z, cum.y); cum.y += wa.z;
    float om2 = fmaf(0.5f, wb.x, cum.z); cum.z += wb.x;
    float om3 = fmaf(0.5f, wb.z, cum.w); cum.w += wb.z;

    float4 dTdp;
    if (k == 0) {
      float idp = 1.f / (pl[1] - pl[0]);
      dTdp.x = (Tp.x - Tc.x) * idp; dTdp.y = (Tp.y - Tc.y) * idp;
      dTdp.z = (Tp.z - Tc.z) * idp; dTdp.w = (Tp.w - Tc.w) * idp;
    } else if (k == Kz - 1) {
      float idp = 1.f / (pl[Kz - 1] - pl[Kz - 2]);
      dTdp.x = (Tc.x - Tm.x) * idp; dTdp.y = (Tc.y - Tm.y) * idp;
      dTdp.z = (Tc.z - Tm.z) * idp; dTdp.w = (Tc.w - Tm.w) * idp;
    } else {
      float idp = 1.f / (pl[k + 1] - pl[k - 1]);
      dTdp.x = (Tp.x - Tm.x) * idp; dTdp.y = (Tp.y - Tm.y) * idp;
      dTdp.z = (Tp.z - Tm.z) * idp; dTdp.w = (Tp.w - Tm.w) * idp;
    }
    float iplk = RCP / pl[k];
    float4 dt = dT4[k * (HW / 4) + i4];
    dt.x += om0 * fmaf(iplk, Tc.x, -dTdp.x);
    dt.y += om1 * fmaf(iplk, Tc.y, -dTdp.y);
    dt.z += om2 * fmaf(iplk, Tc.z, -dTdp.z);
    dt.w += om3 * fmaf(iplk, Tc.w, -dTdp.w);
    dT4[k * (HW / 4) + i4] = dt;

    float4 oa = o4[k * (HW / 2) + 2 * i4];
    float4 ob = o4[k * (HW / 2) + 2 * i4 + 1];
    oa.y += sumT.x; oa.w += sumT.y;
    ob.y += sumT.z; ob.w += sumT.w;
    o4[k * (HW / 2) + 2 * i4] = oa;
    o4[k * (HW / 2) + 2 * i4 + 1] = ob;

    if (k < Kz - 1) {
      float c = -287.0f * logf(pl[k] / pl[k + 1]) * invR;
      sumT.x = fmaf(c, wa.y, sumT.x);
      sumT.y = fmaf(c, wa.w, sumT.y);
      sumT.z = fmaf(c, wb.y, sumT.z);
      sumT.w = fmaf(c, wb.w, sumT.w);
    }
    Tm = Tc; Tc = Tp;
  }
}

// ------------------------------------------------- fallback fused kernel ----
constexpr int FTH = 16, FTW = 16;
constexpr int FSH = FTH + 8, FSW = FTW + 8;
constexpr int FEH = FTH + 4, FEW = FTW + 4;
constexpr int FSWp = FSW + 1, FEWp = FEW + 1;

__global__ __launch_bounds__(256) void pe_step(
    const float2* __restrict__ uv,
    const float*  __restrict__ Tg,
    const float*  __restrict__ qg,
    const float*  __restrict__ psi,
    const float*  __restrict__ quad,
    const float*  __restrict__ f_cor,
    const float*  __restrict__ p_levels,
    const float*  __restrict__ delta_p,
    float* __restrict__ out)
{
  __shared__ float uS[FSH][FSWp], vS[FSH][FSWp], TS[FSH][FSWp], qS[FSH][FSWp];
  __shared__ float keS[FEH][FEWp];
  __shared__ float d1uS[FEH][FEWp], d1vS[FEH][FEWp], d1TS[FEH][FEWp], d1qS[FEH][FEWp];
  __shared__ float P1L[FEH][25];
  __shared__ float P0L[FTH][25];
  __shared__ float quadA[FSH];
  __shared__ float pl[8], dps[8];

  const int tid = threadIdx.x;
  const int tx = tid & (FTW - 1);
  const int ty = tid >> 4;
  const int w0 = blockIdx.x * FTW;
  const int h0 = blockIdx.y * FTH;

  if (tid < FSH) quadA[tid] = quad[clipH(h0 + tid - 4)];
  if (tid < 8) { pl[tid] = p_levels[tid]; dps[tid] = delta_p[tid]; }
  for (int idx = tid; idx < FEH * 25; idx += 256) {
    int ee = idx / 25, t = idx - ee * 25;
    int p = clipH(h0 + ee - 2);
    float s = 0.f;
    #pragma unroll
    for (int kk = 0; kk < 5; ++kk)
      s += psi[kk * (2 * Hh * 25) + Hh * 25 + p * 25 + t];
    P1L[ee][t] = s;
  }
  for (int idx = tid; idx < FTH * 25; idx += 256) {
    int r = idx / 25, t = idx - r * 25;
    int p = clipH(h0 + r);
    float s = 0.f;
    #pragma unroll
    for (int kk = 0; kk < 5; ++kk)
      s += psi[kk * (2 * Hh * 25) + p * 25 + t];
    P0L[r][t] = s;
  }
  __syncthreads();

  const int h = h0 + ty;
  const bool act = h < Hh;
  const int hc = act ? h : (Hh - 1);
  const int w = w0 + tx;
  const float f = f_cor[hc];
  const float invR = (float)(1.0 / 6371000.0);
  const float cL = 200000.0f * invR * invR;
  const float RCP = (float)(287.0 / 1004.0);

  float cum = 0.f;
  float sumT = 0.f;

  #pragma unroll 1
  for (int k = 0; k < Kz; ++k) {
    __syncthreads();
    for (int idx = tid; idx < FSH * FSW; idx += 256) {
      int rr = idx / FSW, cc = idx - rr * FSW;
      int pr = clipH(h0 + rr - 4);
      int pc = w0 + cc - 4;
      pc = pc < 0 ? pc + Ww : (pc >= Ww ? pc - Ww : pc);
      int g = (k * Hh + pr) * Ww + pc;
      float2 uvv = uv[g];
      uS[rr][cc] = uvv.x; vS[rr][cc] = uvv.y;
      TS[rr][cc] = Tg[g]; qS[rr][cc] = qg[g];
    }
    __syncthreads();
    for (int idx = tid; idx < FEH * FEW; idx += 256) {
      int ee = idx / FEW, ec = idx - ee * FEW;
      float su = uS[ee + 2][ec + 2], sv = vS[ee + 2][ec + 2];
      keS[ee][ec] = 0.5f * (su * su + sv * sv);
    }
    for (int idx = tid; idx < FEH * FEW; idx += 256) {
      int ee = idx / FEW, ec = idx - ee * FEW;
      int p = clipH(h0 + ee - 2);
      float au = 0.f, av = 0.f, aT = 0.f, aq = 0.f;
      #pragma unroll
      for (int dl = 0; dl < 5; ++dl) {
        int sp = clipH(p + dl - 2);
        int rr = sp - h0 + 4;
        float qv = quadA[rr];
        float ru = 0.f, rv = 0.f, rT = 0.f, rq = 0.f;
        #pragma unroll
        for (int dw = 0; dw < 5; ++dw) {
          float wgt = P1L[ee][dl * 5 + dw];
          ru = fmaf(wgt, uS[rr][ec + dw], ru);
          rv = fmaf(wgt, vS[rr][ec + dw], rv);
          rT = fmaf(wgt, TS[rr][ec + dw], rT);
          rq = fmaf(wgt, qS[rr][ec + dw], rq);
        }
        au = fmaf(qv, ru, au); av = fmaf(qv, rv, av);
        aT = fmaf(qv, rT, aT); aq = fmaf(qv, rq, aq);
      }
      d1uS[ee][ec] = au; d1vS[ee][ec] = av;
      d1TS[ee][ec] = aT; d1qS[ee][ec] = aq;
    }
    __syncthreads();

    float d0u = 0.f, d1ke = 0.f;
    #pragma unroll
    for (int dl = 0; dl < 5; ++dl) {
      int sp = clipH(hc + dl - 2);
      int rr = sp - h0 + 4;
      int er = sp - h0 + 2;
      float qv = quadA[rr];
      float r0 = 0.f, rk = 0.f;
      #pragma unroll
      for (int dw = 0; dw < 5; ++dw) {
        r0 = fmaf(P0L[ty][dl * 5 + dw], uS[rr][tx + 2 + dw], r0);
        rk = fmaf(P1L[ty + 2][dl * 5 + dw], keS[er][tx + dw], rk);
      }
      d0u = fmaf(qv, r0, d0u);
      d1ke = fmaf(qv, rk, d1ke);
    }

    float lapu = 0.f, lapv = 0.f, lapT = 0.f, lapq = 0.f;
    #pragma unroll
    for (int dl = 0; dl < 5; ++dl) {
      int sp = clipH(hc + dl - 2);
      int er = sp - h0 + 2;
      float qv = quadA[er + 2];
      float ru = 0.f, rv = 0.f, rT = 0.f, rq = 0.f;
      #pragma unroll
      for (int dw = 0; dw < 5; ++dw) {
        float wgt = P1L[ty + 2][dl * 5 + dw];
        ru = fmaf(wgt, d1uS[er][tx + dw], ru);
        rv = fmaf(wgt, d1vS[er][tx + dw], rv);
        rT = fmaf(wgt, d1TS[er][tx + dw], rT);
        rq = fmaf(wgt, d1qS[er][tx + dw], rq);
      }
      lapu = fmaf(qv, ru, lapu); lapv = fmaf(qv, rv, lapv);
      lapT = fmaf(qv, rT, lapT); lapq = fmaf(qv, rq, lapq);
    }

    float d1T_c = d1TS[ty + 2][tx + 2];
    float d1v_c = d1vS[ty + 2][tx + 2];
    float d1q_c = d1qS[ty + 2][tx + 2];
    float uc = uS[ty + 4][tx + 4], vc = vS[ty + 4][tx + 4];
    float Tc = TS[ty + 4][tx + 4];

    float coef1 = fmaf(d0u, invR, -f);
    float duv0 = fmaf(-coef1, vc, cL * lapu);
    float yv1 = fmaf(-invR, d1ke, sumT);
    float duv1 = fmaf(coef1, uc, yv1) + cL * lapv;

    float div = invR * d1v_c;
    float dpk = dps[k];
    float omega = fmaf(0.5f * div, dpk, cum);
    cum = fmaf(div, dpk, cum);

    int gidx = (k * Hh + hc) * Ww + w;
    float dTdp;
    if (k == 0) {
      float Tp = Tg[gidx + HW];
      dTdp = (Tp - Tc) / (pl[1] - pl[0]);
    } else if (k == Kz - 1) {
      float Tm = Tg[gidx - HW];
      dTdp = (Tc - Tm) / (pl[Kz - 1] - pl[Kz - 2]);
    } else {
      float Tp = Tg[gidx + HW];
      float Tm = Tg[gidx - HW];
      dTdp = (Tp - Tm) / (pl[k + 1] - pl[k - 1]);
    }
    float adv = -(invR * d1T_c) * vc;
    float dT = adv + omega * ((RCP * Tc) / pl[k] - dTdp) + cL * lapT;
    float dq = fmaf(-(invR * d1q_c), vc, cL * lapq);

    if (act) {
      ((float2*)out)[(k * Hh + h) * Ww + w] = make_float2(duv0, duv1);
      out[OFF_DT + gidx] = dT;
      out[OFF_DQ + gidx] = dq;
    }

    if (k < Kz - 1) {
      float lpr = logf(pl[k] / pl[k + 1]);
      float wTk = (float)(-287.0 * (double)lpr / 6371000.0);
      sumT = fmaf(wTk, d1T_c, sumT);
    }
  }
}

extern "C" void kernel_launch(void* const* d_in, const int* in_sizes, int n_in,
                              void* d_out, int out_size, void* d_ws, size_t ws_size,
                              hipStream_t stream) {
  (void)in_sizes; (void)n_in; (void)out_size;
  const float2* uv   = (const float2*)d_in[0];
  const float*  T    = (const float*) d_in[1];
  const float*  q    = (const float*) d_in[2];
  const float*  psi  = (const float*) d_in[3];
  const float*  quad = (const float*) d_in[4];
  const float*  fc   = (const float*) d_in[5];
  const float*  pl   = (const float*) d_in[6];
  const float*  dp   = (const float*) d_in[7];

  const size_t ws_div_floats = (size_t)2 * Kz * HW;        // K*HW float2
  const size_t pq_floats = (size_t)Hh * PQROW;             // 14440
  const size_t w2_floats = (size_t)Hh * W2ROW;             // 38988
  const size_t ws_need = (ws_div_floats + 2 * pq_floats + w2_floats) * sizeof(float);
  if (ws_size >= ws_need) {
    float* wsF = (float*)d_ws;
    float* P0g = wsF + ws_div_floats;
    float* P1g = P0g + pq_floats;
    float* W2g = P1g + pq_floats;

    dim3 gt1((Hh * PQROW + 255) / 256);                    // 57 blocks
    hipLaunchKernelGGL(pe_tab_pq, gt1, dim3(256), 0, stream, psi, quad, P0g, P1g);

    dim3 gt2((Hh * 9 + 255) / 256);                        // 13 blocks
    hipLaunchKernelGGL(pe_tab_w2, gt2, dim3(256), 0, stream, P1g, W2g);

    dim3 g1((Ww + TW - 1) / TW, (Hh + TH - 1) / TH, Kz);   // 12 x 23 x 8
    hipLaunchKernelGGL(pe_pass1, g1, dim3(256), 0, stream,
                       uv, T, q, P0g, P1g, W2g, fc, dp, (float*)d_out, (float2*)d_ws);

    dim3 g2((HW / 4 + 255) / 256);
    hipLaunchKernelGGL(pe_pass2, g2, dim3(256), 0, stream,
                       T, pl, (const float2*)d_ws, (float*)d_out);
  } else {
    dim3 grid(Ww / FTW, (Hh + FTH - 1) / FTH);
    hipLaunchKernelGGL(pe_step, grid, dim3(256), 0, stream,
                       uv, T, q, psi, quad, fc, pl, dp, (float*)d_out);
  }
}

// Round 11
// 71.109 us; speedup vs baseline: 30.1587x; 1.2847x over previous
//
#include <hip/hip_runtime.h>

// Primitive-equations block stepper, gfx950 — R11.
// R6 two-stage structure (FLOP-optimal: ext-D1 into d1S, then 5x5 stencil2)
// with a smaller tile: TW 64->48, 192 threads, LDS 50.2->38.0 KB -> 4
// blocks/CU resident (was 2-3). R10's fused 9x9 was VALU-heavier and slower.

constexpr int Kz = 8, Hh = 361, Ww = 720;
constexpr int HW = Hh * Ww;              // 259920
constexpr int OFF_DT = Kz * HW * 2;      // 4158720
constexpr int OFF_DQ = OFF_DT + Kz * HW; // 6238080

// ---- pass-1 geometry ----
constexpr int TH = 16, TW = 48;          // outputs per block
constexpr int NTHR = 192;                // 12 thread-cols x 16 rows, 3 waves
constexpr int SH = TH + 8, SW4 = TW + 8; // staged region 24 x 56 points
constexpr int EH = TH + 4, EW4 = TW + 4; // ext D1 region 20 x 52
constexpr int SW4P = 57;                 // S4 row stride (odd mod 8)
constexpr int EW4P = 53;                 // d1S row stride (5 mod 8)
constexpr int PQROW = 40;                // P-table row stride: 5 a-groups x 8

__device__ __forceinline__ int clipH(int x) {
  return x < 0 ? 0 : (x > Hh - 1 ? Hh - 1 : x);
}

#define FMA4(acc, s, v)                                                        \
  do {                                                                         \
    acc.x = fmaf((s), (v).x, acc.x);                                           \
    acc.y = fmaf((s), (v).y, acc.y);                                           \
    acc.z = fmaf((s), (v).z, acc.z);                                           \
    acc.w = fmaf((s), (v).w, acc.w);                                           \
  } while (0)

#define ROWV(acc, a, b, c, d, e)                                               \
  do {                                                                         \
    FMA4(acc, wq0, a); FMA4(acc, wq1, b); FMA4(acc, wq2, c);                   \
    FMA4(acc, wq3, d); FMA4(acc, wq4, e);                                      \
  } while (0)

#define ROW5S(acc, q0, q1, q2, q3, q4, a, b, c, d, e)                          \
  acc = fmaf(q0, a, fmaf(q1, b, fmaf(q2, c, fmaf(q3, d, fmaf(q4, e, acc)))))

// ---------------------------------------------------- P0q/P1q tables --------
__global__ __launch_bounds__(256) void pe_tab_pq(
    const float* __restrict__ psi,
    const float* __restrict__ quad,
    float* __restrict__ P0g,
    float* __restrict__ P1g)
{
  int idx = blockIdx.x * 256 + threadIdx.x;   // h*40 + a*8 + b
  if (idx >= Hh * PQROW) return;
  int h = idx / PQROW, o = idx - h * PQROW;
  int a = o >> 3, b = o & 7;
  float v0 = 0.f, v1 = 0.f;
  if (b < 5) {
    #pragma unroll
    for (int kk = 0; kk < 5; ++kk) {
      v0 += psi[kk * (2 * Hh * 25) + h * 25 + a * 5 + b];
      v1 += psi[kk * (2 * Hh * 25) + Hh * 25 + h * 25 + a * 5 + b];
    }
    float qv = quad[clipH(h + a - 2)];
    v0 *= qv; v1 *= qv;
  }
  P0g[idx] = v0;
  P1g[idx] = v1;
}

// ---------------------------------------------------------------- pass 1 ----
__global__ __launch_bounds__(NTHR) void pe_pass1(
    const float2* __restrict__ uv,
    const float*  __restrict__ Tg,
    const float*  __restrict__ qg,
    const float*  __restrict__ P0g,
    const float*  __restrict__ P1g,
    const float*  __restrict__ f_cor,
    const float*  __restrict__ delta_p,
    float* __restrict__ out,
    float2* __restrict__ ws)
{
  __shared__ float4 S4[SH][SW4P];       // (u,v,T,q), 21.4 KB
  __shared__ float4 d1S[EH][EW4P];      // (d1u,d1v,d1T,d1q), 16.6 KB

  const int tid = threadIdx.x;
  const int tx = tid % 12;              // thread col (owns 4 outputs)
  const int ty = tid / 12;              // thread row 0..15
  const int w0 = blockIdx.x * TW;
  const int h0 = blockIdx.y * TH;
  const int k  = blockIdx.z;

  // ---- stage (u,v,T,q) as float4 with +-4 halo (clip lat, wrap lon) ----
  for (int idx = tid; idx < SH * SW4; idx += NTHR) {
    int rr = idx / SW4, cc = idx - rr * SW4;
    int pr = clipH(h0 + rr - 4);
    int pc = w0 + cc - 4;
    pc = pc < 0 ? pc + Ww : (pc >= Ww ? pc - Ww : pc);
    int g = (k * Hh + pr) * Ww + pc;
    float2 uvv = uv[g];
    S4[rr][cc] = make_float4(uvv.x, uvv.y, Tg[g], qg[g]);
  }
  __syncthreads();

  // ---- extended D1 of (u,v,T,q): 20 x 13 groups, ee-fastest lane map ----
  for (int idx = tid; idx < EH * (EW4 / 4); idx += NTHR) {
    int ee = idx % EH;                  // row fastest -> wave spans rows
    int gc = idx / EH;                  // 0..12
    int cb = gc * 4;
    int p = clipH(h0 + ee - 2);
    const float* Pr = P1g + p * PQROW;
    float4 a0 = {0,0,0,0}, a1 = {0,0,0,0}, a2 = {0,0,0,0}, a3 = {0,0,0,0};
    #pragma unroll
    for (int dl = 0; dl < 5; ++dl) {
      int sp = clipH(p + dl - 2);
      int rr = sp - h0 + 4;
      const float4* row = &S4[rr][cb];
      float4 g0 = row[0], g1 = row[1], g2 = row[2], g3 = row[3];
      float4 g4 = row[4], g5 = row[5], g6 = row[6], g7 = row[7];
      float4 wA = *(const float4*)(Pr + dl * 8);
      float wq0 = wA.x, wq1 = wA.y, wq2 = wA.z, wq3 = wA.w;
      float wq4 = Pr[dl * 8 + 4];
      ROWV(a0, g0, g1, g2, g3, g4);
      ROWV(a1, g1, g2, g3, g4, g5);
      ROWV(a2, g2, g3, g4, g5, g6);
      ROWV(a3, g3, g4, g5, g6, g7);
    }
    d1S[ee][cb + 0] = a0; d1S[ee][cb + 1] = a1;
    d1S[ee][cb + 2] = a2; d1S[ee][cb + 3] = a3;
  }
  __syncthreads();

  const int h = h0 + ty;
  const int hc = h < Hh ? h : (Hh - 1);
  const int wbase = w0 + tx * 4;
  const float f = f_cor[hc];
  const float invR = (float)(1.0 / 6371000.0);
  const float halfInvR = 0.5f * invR;
  const float cL = 200000.0f * invR * invR;
  const float* Pr1 = P1g + hc * PQROW;
  const float* Pr0 = P0g + hc * PQROW;

  // ---- second stencil: laplacians (d1S), D0(u) & D1(u^2+v^2) (S4) ----
  float4 lp0 = {0,0,0,0}, lp1 = {0,0,0,0}, lp2 = {0,0,0,0}, lp3 = {0,0,0,0};
  float du0 = 0.f, du1 = 0.f, du2 = 0.f, du3 = 0.f;   // D0(u)
  float dk0 = 0.f, dk1 = 0.f, dk2 = 0.f, dk3 = 0.f;   // D1(u^2+v^2)
  #pragma unroll
  for (int dl = 0; dl < 5; ++dl) {
    int sp = clipH(hc + dl - 2);
    int er = sp - h0 + 2;               // d1S row
    int rr = er + 2;                    // S4 row
    float4 wA = *(const float4*)(Pr1 + dl * 8);
    float wq0 = wA.x, wq1 = wA.y, wq2 = wA.z, wq3 = wA.w;
    float wq4 = Pr1[dl * 8 + 4];
    {
      const float4* row = &d1S[er][tx * 4];
      float4 g0 = row[0], g1 = row[1], g2 = row[2], g3 = row[3];
      float4 g4 = row[4], g5 = row[5], g6 = row[6], g7 = row[7];
      ROWV(lp0, g0, g1, g2, g3, g4);
      ROWV(lp1, g1, g2, g3, g4, g5);
      ROWV(lp2, g2, g3, g4, g5, g6);
      ROWV(lp3, g3, g4, g5, g6, g7);
    }
    {
      const float4* srow = &S4[rr][tx * 4 + 2];
      float4 s0 = srow[0], s1 = srow[1], s2 = srow[2], s3 = srow[3];
      float4 s4 = srow[4], s5 = srow[5], s6 = srow[6], s7 = srow[7];
      float k0 = fmaf(s0.y, s0.y, s0.x * s0.x);
      float k1 = fmaf(s1.y, s1.y, s1.x * s1.x);
      float k2 = fmaf(s2.y, s2.y, s2.x * s2.x);
      float k3 = fmaf(s3.y, s3.y, s3.x * s3.x);
      float k4 = fmaf(s4.y, s4.y, s4.x * s4.x);
      float k5 = fmaf(s5.y, s5.y, s5.x * s5.x);
      float k6 = fmaf(s6.y, s6.y, s6.x * s6.x);
      float k7 = fmaf(s7.y, s7.y, s7.x * s7.x);
      ROW5S(dk0, wq0, wq1, wq2, wq3, wq4, k0, k1, k2, k3, k4);
      ROW5S(dk1, wq0, wq1, wq2, wq3, wq4, k1, k2, k3, k4, k5);
      ROW5S(dk2, wq0, wq1, wq2, wq3, wq4, k2, k3, k4, k5, k6);
      ROW5S(dk3, wq0, wq1, wq2, wq3, wq4, k3, k4, k5, k6, k7);
      float4 w0A = *(const float4*)(Pr0 + dl * 8);
      float q0 = w0A.x, q1 = w0A.y, q2 = w0A.z, q3 = w0A.w;
      float q4 = Pr0[dl * 8 + 4];
      ROW5S(du0, q0, q1, q2, q3, q4, s0.x, s1.x, s2.x, s3.x, s4.x);
      ROW5S(du1, q0, q1, q2, q3, q4, s1.x, s2.x, s3.x, s4.x, s5.x);
      ROW5S(du2, q0, q1, q2, q3, q4, s2.x, s3.x, s4.x, s5.x, s6.x);
      ROW5S(du3, q0, q1, q2, q3, q4, s3.x, s4.x, s5.x, s6.x, s7.x);
    }
  }

  if (h < Hh && wbase < Ww) {
    const float dpk = delta_p[k];
    float4 duvA, duvB, dTv, dqv, wsA, wsB;
    {
      float4 d1c = d1S[ty + 2][tx * 4 + 2];
      float4 ctr = S4[ty + 4][tx * 4 + 4];
      float coef1 = fmaf(du0, invR, -f);
      duvA.x = fmaf(-coef1, ctr.y, cL * lp0.x);
      duvA.y = fmaf(coef1, ctr.x, -halfInvR * dk0) + cL * lp0.y;
      dTv.x = -(invR * d1c.z) * ctr.y + cL * lp0.z;
      dqv.x = fmaf(-(invR * d1c.w), ctr.y, cL * lp0.w);
      wsA.x = invR * d1c.y * dpk; wsA.y = d1c.z;
    }
    {
      float4 d1c = d1S[ty + 2][tx * 4 + 3];
      float4 ctr = S4[ty + 4][tx * 4 + 5];
      float coef1 = fmaf(du1, invR, -f);
      duvA.z = fmaf(-coef1, ctr.y, cL * lp1.x);
      duvA.w = fmaf(coef1, ctr.x, -halfInvR * dk1) + cL * lp1.y;
      dTv.y = -(invR * d1c.z) * ctr.y + cL * lp1.z;
      dqv.y = fmaf(-(invR * d1c.w), ctr.y, cL * lp1.w);
      wsA.z = invR * d1c.y * dpk; wsA.w = d1c.z;
    }
    {
      float4 d1c = d1S[ty + 2][tx * 4 + 4];
      float4 ctr = S4[ty + 4][tx * 4 + 6];
      float coef1 = fmaf(du2, invR, -f);
      duvB.x = fmaf(-coef1, ctr.y, cL * lp2.x);
      duvB.y = fmaf(coef1, ctr.x, -halfInvR * dk2) + cL * lp2.y;
      dTv.z = -(invR * d1c.z) * ctr.y + cL * lp2.z;
      dqv.z = fmaf(-(invR * d1c.w), ctr.y, cL * lp2.w);
      wsB.x = invR * d1c.y * dpk; wsB.y = d1c.z;
    }
    {
      float4 d1c = d1S[ty + 2][tx * 4 + 5];
      float4 ctr = S4[ty + 4][tx * 4 + 7];
      float coef1 = fmaf(du3, invR, -f);
      duvB.z = fmaf(-coef1, ctr.y, cL * lp3.x);
      duvB.w = fmaf(coef1, ctr.x, -halfInvR * dk3) + cL * lp3.y;
      dTv.w = -(invR * d1c.z) * ctr.y + cL * lp3.z;
      dqv.w = fmaf(-(invR * d1c.w), ctr.y, cL * lp3.w);
      wsB.z = invR * d1c.y * dpk; wsB.w = d1c.z;
    }
    const int gidx = (k * Hh + h) * Ww + wbase;
    float4* o4 = (float4*)out;
    o4[gidx >> 1] = duvA;
    o4[(gidx >> 1) + 1] = duvB;
    *(float4*)&out[OFF_DT + gidx] = dTv;
    *(float4*)&out[OFF_DQ + gidx] = dqv;
    float4* w4 = (float4*)ws;
    w4[gidx >> 1] = wsA;
    w4[(gidx >> 1) + 1] = wsB;
  }
}

// ---------------------------------------------------------------- pass 2 ----
__global__ __launch_bounds__(256) void pe_pass2(
    const float* __restrict__ Tg,
    const float* __restrict__ p_levels,
    const float2* __restrict__ ws,
    float* __restrict__ out)
{
  int i4 = blockIdx.x * 256 + threadIdx.x;   // quad index (4 points/thread)
  if (i4 >= HW / 4) return;
  const float invR = (float)(1.0 / 6371000.0);
  const float RCP = (float)(287.0 / 1004.0);

  float pl[Kz];
  #pragma unroll
  for (int k = 0; k < Kz; ++k) pl[k] = p_levels[k];

  const float4* T4 = (const float4*)Tg;
  const float4* ws4 = (const float4*)ws;
  float4* o4 = (float4*)out;
  float4* dT4 = (float4*)(out + OFF_DT);

  float4 cum = {0,0,0,0}, sumT = {0,0,0,0};
  float4 Tm = {0,0,0,0}, Tc = T4[i4];

  #pragma unroll
  for (int k = 0; k < Kz; ++k) {
    float4 Tp = (k < Kz - 1) ? T4[(k + 1) * (HW / 4) + i4] : make_float4(0,0,0,0);
    float4 wa = ws4[k * (HW / 2) + 2 * i4];
    float4 wb = ws4[k * (HW / 2) + 2 * i4 + 1];
    float om0 = fmaf(0.5f, wa.x, cum.x); cum.x += wa.x;
    float om1 = fmaf(0.5f, wa.z, cum.y); cum.y += wa.z;
    float om2 = fmaf(0.5f, wb.x, cum.z); cum.z += wb.x;
    float om3 = fmaf(0.5f, wb.z, cum.w); cum.w += wb.z;

    float4 dTdp;
    if (k == 0) {
      float idp = 1.f / (pl[1] - pl[0]);
      dTdp.x = (Tp.x - Tc.x) * idp; dTdp.y = (Tp.y - Tc.y) * idp;
      dTdp.z = (Tp.z - Tc.z) * idp; dTdp.w = (Tp.w - Tc.w) * idp;
    } else if (k == Kz - 1) {
      float idp = 1.f / (pl[Kz - 1] - pl[Kz - 2]);
      dTdp.x = (Tc.x - Tm.x) * idp; dTdp.y = (Tc.y - Tm.y) * idp;
      dTdp.z = (Tc.z - Tm.z) * idp; dTdp.w = (Tc.w - Tm.w) * idp;
    } else {
      float idp = 1.f / (pl[k + 1] - pl[k - 1]);
      dTdp.x = (Tp.x - Tm.x) * idp; dTdp.y = (Tp.y - Tm.y) * idp;
      dTdp.z = (Tp.z - Tm.z) * idp; dTdp.w = (Tp.w - Tm.w) * idp;
    }
    float iplk = RCP / pl[k];
    float4 dt = dT4[k * (HW / 4) + i4];
    dt.x += om0 * fmaf(iplk, Tc.x, -dTdp.x);
    dt.y += om1 * fmaf(iplk, Tc.y, -dTdp.y);
    dt.z += om2 * fmaf(iplk, Tc.z, -dTdp.z);
    dt.w += om3 * fmaf(iplk, Tc.w, -dTdp.w);
    dT4[k * (HW / 4) + i4] = dt;

    float4 oa = o4[k * (HW / 2) + 2 * i4];
    float4 ob = o4[k * (HW / 2) + 2 * i4 + 1];
    oa.y += sumT.x; oa.w += sumT.y;
    ob.y += sumT.z; ob.w += sumT.w;
    o4[k * (HW / 2) + 2 * i4] = oa;
    o4[k * (HW / 2) + 2 * i4 + 1] = ob;

    if (k < Kz - 1) {
      float c = -287.0f * logf(pl[k] / pl[k + 1]) * invR;
      sumT.x = fmaf(c, wa.y, sumT.x);
      sumT.y = fmaf(c, wa.w, sumT.y);
      sumT.z = fmaf(c, wb.y, sumT.z);
      sumT.w = fmaf(c, wb.w, sumT.w);
    }
    Tm = Tc; Tc = Tp;
  }
}

// ------------------------------------------------- fallback fused kernel ----
constexpr int FTH = 16, FTW = 16;
constexpr int FSH = FTH + 8, FSW = FTW + 8;
constexpr int FEH = FTH + 4, FEW = FTW + 4;
constexpr int FSWp = FSW + 1, FEWp = FEW + 1;

__global__ __launch_bounds__(256) void pe_step(
    const float2* __restrict__ uv,
    const float*  __restrict__ Tg,
    const float*  __restrict__ qg,
    const float*  __restrict__ psi,
    const float*  __restrict__ quad,
    const float*  __restrict__ f_cor,
    const float*  __restrict__ p_levels,
    const float*  __restrict__ delta_p,
    float* __restrict__ out)
{
  __shared__ float uS[FSH][FSWp], vS[FSH][FSWp], TS[FSH][FSWp], qS[FSH][FSWp];
  __shared__ float keS[FEH][FEWp];
  __shared__ float d1uS[FEH][FEWp], d1vS[FEH][FEWp], d1TS[FEH][FEWp], d1qS[FEH][FEWp];
  __shared__ float P1L[FEH][25];
  __shared__ float P0L[FTH][25];
  __shared__ float quadA[FSH];
  __shared__ float pl[8], dps[8];

  const int tid = threadIdx.x;
  const int tx = tid & (FTW - 1);
  const int ty = tid >> 4;
  const int w0 = blockIdx.x * FTW;
  const int h0 = blockIdx.y * FTH;

  if (tid < FSH) quadA[tid] = quad[clipH(h0 + tid - 4)];
  if (tid < 8) { pl[tid] = p_levels[tid]; dps[tid] = delta_p[tid]; }
  for (int idx = tid; idx < FEH * 25; idx += 256) {
    int ee = idx / 25, t = idx - ee * 25;
    int p = clipH(h0 + ee - 2);
    float s = 0.f;
    #pragma unroll
    for (int kk = 0; kk < 5; ++kk)
      s += psi[kk * (2 * Hh * 25) + Hh * 25 + p * 25 + t];
    P1L[ee][t] = s;
  }
  for (int idx = tid; idx < FTH * 25; idx += 256) {
    int r = idx / 25, t = idx - r * 25;
    int p = clipH(h0 + r);
    float s = 0.f;
    #pragma unroll
    for (int kk = 0; kk < 5; ++kk)
      s += psi[kk * (2 * Hh * 25) + p * 25 + t];
    P0L[r][t] = s;
  }
  __syncthreads();

  const int h = h0 + ty;
  const bool act = h < Hh;
  const int hc = act ? h : (Hh - 1);
  const int w = w0 + tx;
  const float f = f_cor[hc];
  const float invR = (float)(1.0 / 6371000.0);
  const float cL = 200000.0f * invR * invR;
  const float RCP = (float)(287.0 / 1004.0);

  float cum = 0.f;
  float sumT = 0.f;

  #pragma unroll 1
  for (int k = 0; k < Kz; ++k) {
    __syncthreads();
    for (int idx = tid; idx < FSH * FSW; idx += 256) {
      int rr = idx / FSW, cc = idx - rr * FSW;
      int pr = clipH(h0 + rr - 4);
      int pc = w0 + cc - 4;
      pc = pc < 0 ? pc + Ww : (pc >= Ww ? pc - Ww : pc);
      int g = (k * Hh + pr) * Ww + pc;
      float2 uvv = uv[g];
      uS[rr][cc] = uvv.x; vS[rr][cc] = uvv.y;
      TS[rr][cc] = Tg[g]; qS[rr][cc] = qg[g];
    }
    __syncthreads();
    for (int idx = tid; idx < FEH * FEW; idx += 256) {
      int ee = idx / FEW, ec = idx - ee * FEW;
      float su = uS[ee + 2][ec + 2], sv = vS[ee + 2][ec + 2];
      keS[ee][ec] = 0.5f * (su * su + sv * sv);
    }
    for (int idx = tid; idx < FEH * FEW; idx += 256) {
      int ee = idx / FEW, ec = idx - ee * FEW;
      int p = clipH(h0 + ee - 2);
      float au = 0.f, av = 0.f, aT = 0.f, aq = 0.f;
      #pragma unroll
      for (int dl = 0; dl < 5; ++dl) {
        int sp = clipH(p + dl - 2);
        int rr = sp - h0 + 4;
        float qv = quadA[rr];
        float ru = 0.f, rv = 0.f, rT = 0.f, rq = 0.f;
        #pragma unroll
        for (int dw = 0; dw < 5; ++dw) {
          float wgt = P1L[ee][dl * 5 + dw];
          ru = fmaf(wgt, uS[rr][ec + dw], ru);
          rv = fmaf(wgt, vS[rr][ec + dw], rv);
          rT = fmaf(wgt, TS[rr][ec + dw], rT);
          rq = fmaf(wgt, qS[rr][ec + dw], rq);
        }
        au = fmaf(qv, ru, au); av = fmaf(qv, rv, av);
        aT = fmaf(qv, rT, aT); aq = fmaf(qv, rq, aq);
      }
      d1uS[ee][ec] = au; d1vS[ee][ec] = av;
      d1TS[ee][ec] = aT; d1qS[ee][ec] = aq;
    }
    __syncthreads();

    float d0u = 0.f, d1ke = 0.f;
    #pragma unroll
    for (int dl = 0; dl < 5; ++dl) {
      int sp = clipH(hc + dl - 2);
      int rr = sp - h0 + 4;
      int er = sp - h0 + 2;
      float qv = quadA[rr];
      float r0 = 0.f, rk = 0.f;
      #pragma unroll
      for (int dw = 0; dw < 5; ++dw) {
        r0 = fmaf(P0L[ty][dl * 5 + dw], uS[rr][tx + 2 + dw], r0);
        rk = fmaf(P1L[ty + 2][dl * 5 + dw], keS[er][tx + dw], rk);
      }
      d0u = fmaf(qv, r0, d0u);
      d1ke = fmaf(qv, rk, d1ke);
    }

    float lapu = 0.f, lapv = 0.f, lapT = 0.f, lapq = 0.f;
    #pragma unroll
    for (int dl = 0; dl < 5; ++dl) {
      int sp = clipH(hc + dl - 2);
      int er = sp - h0 + 2;
      float qv = quadA[er + 2];
      float ru = 0.f, rv = 0.f, rT = 0.f, rq = 0.f;
      #pragma unroll
      for (int dw = 0; dw < 5; ++dw) {
        float wgt = P1L[ty + 2][dl * 5 + dw];
        ru = fmaf(wgt, d1uS[er][tx + dw], ru);
        rv = fmaf(wgt, d1vS[er][tx + dw], rv);
        rT = fmaf(wgt, d1TS[er][tx + dw], rT);
        rq = fmaf(wgt, d1qS[er][tx + dw], rq);
      }
      lapu = fmaf(qv, ru, lapu); lapv = fmaf(qv, rv, lapv);
      lapT = fmaf(qv, rT, lapT); lapq = fmaf(qv, rq, lapq);
    }

    float d1T_c = d1TS[ty + 2][tx + 2];
    float d1v_c = d1vS[ty + 2][tx + 2];
    float d1q_c = d1qS[ty + 2][tx + 2];
    float uc = uS[ty + 4][tx + 4], vc = vS[ty + 4][tx + 4];
    float Tc = TS[ty + 4][tx + 4];

    float coef1 = fmaf(d0u, invR, -f);
    float duv0 = fmaf(-coef1, vc, cL * lapu);
    float yv1 = fmaf(-invR, d1ke, sumT);
    float duv1 = fmaf(coef1, uc, yv1) + cL * lapv;

    float div = invR * d1v_c;
    float dpk = dps[k];
    float omega = fmaf(0.5f * div, dpk, cum);
    cum = fmaf(div, dpk, cum);

    int gidx = (k * Hh + hc) * Ww + w;
    float dTdp;
    if (k == 0) {
      float Tp = Tg[gidx + HW];
      dTdp = (Tp - Tc) / (pl[1] - pl[0]);
    } else if (k == Kz - 1) {
      float Tm = Tg[gidx - HW];
      dTdp = (Tc - Tm) / (pl[Kz - 1] - pl[Kz - 2]);
    } else {
      float Tp = Tg[gidx + HW];
      float Tm = Tg[gidx - HW];
      dTdp = (Tp - Tm) / (pl[k + 1] - pl[k - 1]);
    }
    float adv = -(invR * d1T_c) * vc;
    float dT = adv + omega * ((RCP * Tc) / pl[k] - dTdp) + cL * lapT;
    float dq = fmaf(-(invR * d1q_c), vc, cL * lapq);

    if (act) {
      ((float2*)out)[(k * Hh + h) * Ww + w] = make_float2(duv0, duv1);
      out[OFF_DT + gidx] = dT;
      out[OFF_DQ + gidx] = dq;
    }

    if (k < Kz - 1) {
      float lpr = logf(pl[k] / pl[k + 1]);
      float wTk = (float)(-287.0 * (double)lpr / 6371000.0);
      sumT = fmaf(wTk, d1T_c, sumT);
    }
  }
}

extern "C" void kernel_launch(void* const* d_in, const int* in_sizes, int n_in,
                              void* d_out, int out_size, void* d_ws, size_t ws_size,
                              hipStream_t stream) {
  (void)in_sizes; (void)n_in; (void)out_size;
  const float2* uv   = (const float2*)d_in[0];
  const float*  T    = (const float*) d_in[1];
  const float*  q    = (const float*) d_in[2];
  const float*  psi  = (const float*) d_in[3];
  const float*  quad = (const float*) d_in[4];
  const float*  fc   = (const float*) d_in[5];
  const float*  pl   = (const float*) d_in[6];
  const float*  dp   = (const float*) d_in[7];

  const size_t ws_div_floats = (size_t)2 * Kz * HW;        // K*HW float2
  const size_t pq_floats = (size_t)Hh * PQROW;             // 14440
  const size_t ws_need = (ws_div_floats + 2 * pq_floats) * sizeof(float);
  if (ws_size >= ws_need) {
    float* wsF = (float*)d_ws;
    float* P0g = wsF + ws_div_floats;
    float* P1g = P0g + pq_floats;

    dim3 gt1((Hh * PQROW + 255) / 256);                    // 57 blocks
    hipLaunchKernelGGL(pe_tab_pq, gt1, dim3(256), 0, stream, psi, quad, P0g, P1g);

    dim3 g1(Ww / TW, (Hh + TH - 1) / TH, Kz);              // 15 x 23 x 8
    hipLaunchKernelGGL(pe_pass1, g1, dim3(NTHR), 0, stream,
                       uv, T, q, P0g, P1g, fc, dp, (float*)d_out, (float2*)d_ws);

    dim3 g2((HW / 4 + 255) / 256);
    hipLaunchKernelGGL(pe_pass2, g2, dim3(256), 0, stream,
                       T, pl, (const float2*)d_ws, (float*)d_out);
  } else {
    dim3 grid(Ww / FTW, (Hh + FTH - 1) / FTH);
    hipLaunchKernelGGL(pe_step, grid, dim3(256), 0, stream,
                       uv, T, q, psi, quad, fc, pl, dp, (float*)d_out);
  }
}

// Round 12
// 69.402 us; speedup vs baseline: 30.9006x; 1.0246x over previous
//
#include <hip/hip_runtime.h>

// Primitive-equations block stepper, gfx950 — R12.
// R11 two-stage structure with tile 48x16 -> 32x16 (128 thr, 2 waves):
// LDS 38.9 -> 27.6 KB => 5 blocks/CU resident (was ~2.5), 4232 blocks.
// Note: SQ_LDS_BANK_CONFLICT ≈ 7 cyc per wave-b128 is the inherent
// multi-phase cost of ds_read_b128, not fixable conflicts (R11 analysis).

constexpr int Kz = 8, Hh = 361, Ww = 720;
constexpr int HW = Hh * Ww;              // 259920
constexpr int OFF_DT = Kz * HW * 2;      // 4158720
constexpr int OFF_DQ = OFF_DT + Kz * HW; // 6238080

// ---- pass-1 geometry ----
constexpr int TH = 16, TW = 32;          // outputs per block
constexpr int NTHR = 128;                // 8 thread-cols x 16 rows, 2 waves
constexpr int NCOL = 8;                  // thread columns (4 outputs each)
constexpr int SH = TH + 8, SW4 = TW + 8; // staged region 24 x 40 points
constexpr int EH = TH + 4, EW4 = TW + 4; // ext D1 region 20 x 36
constexpr int SW4P = 41;                 // S4 row stride (1 mod 8)
constexpr int EW4P = 37;                 // d1S row stride (5 mod 8)
constexpr int PQROW = 40;                // P-table row stride: 5 a-groups x 8
constexpr int GX = (Ww + TW - 1) / TW;   // 23 (last tile partial, guarded)

__device__ __forceinline__ int clipH(int x) {
  return x < 0 ? 0 : (x > Hh - 1 ? Hh - 1 : x);
}

#define FMA4(acc, s, v)                                                        \
  do {                                                                         \
    acc.x = fmaf((s), (v).x, acc.x);                                           \
    acc.y = fmaf((s), (v).y, acc.y);                                           \
    acc.z = fmaf((s), (v).z, acc.z);                                           \
    acc.w = fmaf((s), (v).w, acc.w);                                           \
  } while (0)

#define ROWV(acc, a, b, c, d, e)                                               \
  do {                                                                         \
    FMA4(acc, wq0, a); FMA4(acc, wq1, b); FMA4(acc, wq2, c);                   \
    FMA4(acc, wq3, d); FMA4(acc, wq4, e);                                      \
  } while (0)

#define ROW5S(acc, q0, q1, q2, q3, q4, a, b, c, d, e)                          \
  acc = fmaf(q0, a, fmaf(q1, b, fmaf(q2, c, fmaf(q3, d, fmaf(q4, e, acc)))))

// ---------------------------------------------------- P0q/P1q tables --------
__global__ __launch_bounds__(256) void pe_tab_pq(
    const float* __restrict__ psi,
    const float* __restrict__ quad,
    float* __restrict__ P0g,
    float* __restrict__ P1g)
{
  int idx = blockIdx.x * 256 + threadIdx.x;   // h*40 + a*8 + b
  if (idx >= Hh * PQROW) return;
  int h = idx / PQROW, o = idx - h * PQROW;
  int a = o >> 3, b = o & 7;
  float v0 = 0.f, v1 = 0.f;
  if (b < 5) {
    #pragma unroll
    for (int kk = 0; kk < 5; ++kk) {
      v0 += psi[kk * (2 * Hh * 25) + h * 25 + a * 5 + b];
      v1 += psi[kk * (2 * Hh * 25) + Hh * 25 + h * 25 + a * 5 + b];
    }
    float qv = quad[clipH(h + a - 2)];
    v0 *= qv; v1 *= qv;
  }
  P0g[idx] = v0;
  P1g[idx] = v1;
}

// ---------------------------------------------------------------- pass 1 ----
__global__ __launch_bounds__(NTHR) void pe_pass1(
    const float2* __restrict__ uv,
    const float*  __restrict__ Tg,
    const float*  __restrict__ qg,
    const float*  __restrict__ P0g,
    const float*  __restrict__ P1g,
    const float*  __restrict__ f_cor,
    const float*  __restrict__ delta_p,
    float* __restrict__ out,
    float2* __restrict__ ws)
{
  __shared__ float4 S4[SH][SW4P];       // (u,v,T,q), 15.4 KB
  __shared__ float4 d1S[EH][EW4P];      // (d1u,d1v,d1T,d1q), 11.6 KB

  const int tid = threadIdx.x;
  const int tx = tid % NCOL;            // thread col (owns 4 outputs)
  const int ty = tid / NCOL;            // thread row 0..15
  const int w0 = blockIdx.x * TW;
  const int h0 = blockIdx.y * TH;
  const int k  = blockIdx.z;

  // ---- stage (u,v,T,q) as float4 with +-4 halo (clip lat, wrap lon) ----
  for (int idx = tid; idx < SH * SW4; idx += NTHR) {
    int rr = idx / SW4, cc = idx - rr * SW4;
    int pr = clipH(h0 + rr - 4);
    int pc = w0 + cc - 4;
    pc = pc < 0 ? pc + Ww : (pc >= Ww ? pc - Ww : pc);
    int g = (k * Hh + pr) * Ww + pc;
    float2 uvv = uv[g];
    S4[rr][cc] = make_float4(uvv.x, uvv.y, Tg[g], qg[g]);
  }
  __syncthreads();

  // ---- extended D1 of (u,v,T,q): 20 x 9 groups, ee-fastest lane map ----
  for (int idx = tid; idx < EH * (EW4 / 4); idx += NTHR) {
    int ee = idx % EH;                  // row fastest -> wave spans rows
    int gc = idx / EH;                  // 0..8
    int cb = gc * 4;
    int p = clipH(h0 + ee - 2);
    const float* Pr = P1g + p * PQROW;
    float4 a0 = {0,0,0,0}, a1 = {0,0,0,0}, a2 = {0,0,0,0}, a3 = {0,0,0,0};
    #pragma unroll
    for (int dl = 0; dl < 5; ++dl) {
      int sp = clipH(p + dl - 2);
      int rr = sp - h0 + 4;
      const float4* row = &S4[rr][cb];
      float4 g0 = row[0], g1 = row[1], g2 = row[2], g3 = row[3];
      float4 g4 = row[4], g5 = row[5], g6 = row[6], g7 = row[7];
      float4 wA = *(const float4*)(Pr + dl * 8);
      float wq0 = wA.x, wq1 = wA.y, wq2 = wA.z, wq3 = wA.w;
      float wq4 = Pr[dl * 8 + 4];
      ROWV(a0, g0, g1, g2, g3, g4);
      ROWV(a1, g1, g2, g3, g4, g5);
      ROWV(a2, g2, g3, g4, g5, g6);
      ROWV(a3, g3, g4, g5, g6, g7);
    }
    d1S[ee][cb + 0] = a0; d1S[ee][cb + 1] = a1;
    d1S[ee][cb + 2] = a2; d1S[ee][cb + 3] = a3;
  }
  __syncthreads();

  const int h = h0 + ty;
  const int hc = h < Hh ? h : (Hh - 1);
  const int wbase = w0 + tx * 4;
  const float f = f_cor[hc];
  const float invR = (float)(1.0 / 6371000.0);
  const float halfInvR = 0.5f * invR;
  const float cL = 200000.0f * invR * invR;
  const float* Pr1 = P1g + hc * PQROW;
  const float* Pr0 = P0g + hc * PQROW;

  // ---- second stencil: laplacians (d1S), D0(u) & D1(u^2+v^2) (S4) ----
  float4 lp0 = {0,0,0,0}, lp1 = {0,0,0,0}, lp2 = {0,0,0,0}, lp3 = {0,0,0,0};
  float du0 = 0.f, du1 = 0.f, du2 = 0.f, du3 = 0.f;   // D0(u)
  float dk0 = 0.f, dk1 = 0.f, dk2 = 0.f, dk3 = 0.f;   // D1(u^2+v^2)
  #pragma unroll
  for (int dl = 0; dl < 5; ++dl) {
    int sp = clipH(hc + dl - 2);
    int er = sp - h0 + 2;               // d1S row
    int rr = er + 2;                    // S4 row
    float4 wA = *(const float4*)(Pr1 + dl * 8);
    float wq0 = wA.x, wq1 = wA.y, wq2 = wA.z, wq3 = wA.w;
    float wq4 = Pr1[dl * 8 + 4];
    {
      const float4* row = &d1S[er][tx * 4];
      float4 g0 = row[0], g1 = row[1], g2 = row[2], g3 = row[3];
      float4 g4 = row[4], g5 = row[5], g6 = row[6], g7 = row[7];
      ROWV(lp0, g0, g1, g2, g3, g4);
      ROWV(lp1, g1, g2, g3, g4, g5);
      ROWV(lp2, g2, g3, g4, g5, g6);
      ROWV(lp3, g3, g4, g5, g6, g7);
    }
    {
      const float4* srow = &S4[rr][tx * 4 + 2];
      float4 s0 = srow[0], s1 = srow[1], s2 = srow[2], s3 = srow[3];
      float4 s4 = srow[4], s5 = srow[5], s6 = srow[6], s7 = srow[7];
      float k0 = fmaf(s0.y, s0.y, s0.x * s0.x);
      float k1 = fmaf(s1.y, s1.y, s1.x * s1.x);
      float k2 = fmaf(s2.y, s2.y, s2.x * s2.x);
      float k3 = fmaf(s3.y, s3.y, s3.x * s3.x);
      float k4 = fmaf(s4.y, s4.y, s4.x * s4.x);
      float k5 = fmaf(s5.y, s5.y, s5.x * s5.x);
      float k6 = fmaf(s6.y, s6.y, s6.x * s6.x);
      float k7 = fmaf(s7.y, s7.y, s7.x * s7.x);
      ROW5S(dk0, wq0, wq1, wq2, wq3, wq4, k0, k1, k2, k3, k4);
      ROW5S(dk1, wq0, wq1, wq2, wq3, wq4, k1, k2, k3, k4, k5);
      ROW5S(dk2, wq0, wq1, wq2, wq3, wq4, k2, k3, k4, k5, k6);
      ROW5S(dk3, wq0, wq1, wq2, wq3, wq4, k3, k4, k5, k6, k7);
      float4 w0A = *(const float4*)(Pr0 + dl * 8);
      float q0 = w0A.x, q1 = w0A.y, q2 = w0A.z, q3 = w0A.w;
      float q4 = Pr0[dl * 8 + 4];
      ROW5S(du0, q0, q1, q2, q3, q4, s0.x, s1.x, s2.x, s3.x, s4.x);
      ROW5S(du1, q0, q1, q2, q3, q4, s1.x, s2.x, s3.x, s4.x, s5.x);
      ROW5S(du2, q0, q1, q2, q3, q4, s2.x, s3.x, s4.x, s5.x, s6.x);
      ROW5S(du3, q0, q1, q2, q3, q4, s3.x, s4.x, s5.x, s6.x, s7.x);
    }
  }

  if (h < Hh && wbase < Ww) {
    const float dpk = delta_p[k];
    float4 duvA, duvB, dTv, dqv, wsA, wsB;
    {
      float4 d1c = d1S[ty + 2][tx * 4 + 2];
      float4 ctr = S4[ty + 4][tx * 4 + 4];
      float coef1 = fmaf(du0, invR, -f);
      duvA.x = fmaf(-coef1, ctr.y, cL * lp0.x);
      duvA.y = fmaf(coef1, ctr.x, -halfInvR * dk0) + cL * lp0.y;
      dTv.x = -(invR * d1c.z) * ctr.y + cL * lp0.z;
      dqv.x = fmaf(-(invR * d1c.w), ctr.y, cL * lp0.w);
      wsA.x = invR * d1c.y * dpk; wsA.y = d1c.z;
    }
    {
      float4 d1c = d1S[ty + 2][tx * 4 + 3];
      float4 ctr = S4[ty + 4][tx * 4 + 5];
      float coef1 = fmaf(du1, invR, -f);
      duvA.z = fmaf(-coef1, ctr.y, cL * lp1.x);
      duvA.w = fmaf(coef1, ctr.x, -halfInvR * dk1) + cL * lp1.y;
      dTv.y = -(invR * d1c.z) * ctr.y + cL * lp1.z;
      dqv.y = fmaf(-(invR * d1c.w), ctr.y, cL * lp1.w);
      wsA.z = invR * d1c.y * dpk; wsA.w = d1c.z;
    }
    {
      float4 d1c = d1S[ty + 2][tx * 4 + 4];
      float4 ctr = S4[ty + 4][tx * 4 + 6];
      float coef1 = fmaf(du2, invR, -f);
      duvB.x = fmaf(-coef1, ctr.y, cL * lp2.x);
      duvB.y = fmaf(coef1, ctr.x, -halfInvR * dk2) + cL * lp2.y;
      dTv.z = -(invR * d1c.z) * ctr.y + cL * lp2.z;
      dqv.z = fmaf(-(invR * d1c.w), ctr.y, cL * lp2.w);
      wsB.x = invR * d1c.y * dpk; wsB.y = d1c.z;
    }
    {
      float4 d1c = d1S[ty + 2][tx * 4 + 5];
      float4 ctr = S4[ty + 4][tx * 4 + 7];
      float coef1 = fmaf(du3, invR, -f);
      duvB.z = fmaf(-coef1, ctr.y, cL * lp3.x);
      duvB.w = fmaf(coef1, ctr.x, -halfInvR * dk3) + cL * lp3.y;
      dTv.w = -(invR * d1c.z) * ctr.y + cL * lp3.z;
      dqv.w = fmaf(-(invR * d1c.w), ctr.y, cL * lp3.w);
      wsB.z = invR * d1c.y * dpk; wsB.w = d1c.z;
    }
    const int gidx = (k * Hh + h) * Ww + wbase;
    float4* o4 = (float4*)out;
    o4[gidx >> 1] = duvA;
    o4[(gidx >> 1) + 1] = duvB;
    *(float4*)&out[OFF_DT + gidx] = dTv;
    *(float4*)&out[OFF_DQ + gidx] = dqv;
    float4* w4 = (float4*)ws;
    w4[gidx >> 1] = wsA;
    w4[(gidx >> 1) + 1] = wsB;
  }
}

// ---------------------------------------------------------------- pass 2 ----
__global__ __launch_bounds__(256) void pe_pass2(
    const float* __restrict__ Tg,
    const float* __restrict__ p_levels,
    const float2* __restrict__ ws,
    float* __restrict__ out)
{
  int i4 = blockIdx.x * 256 + threadIdx.x;   // quad index (4 points/thread)
  if (i4 >= HW / 4) return;
  const float invR = (float)(1.0 / 6371000.0);
  const float RCP = (float)(287.0 / 1004.0);

  float pl[Kz];
  #pragma unroll
  for (int k = 0; k < Kz; ++k) pl[k] = p_levels[k];

  const float4* T4 = (const float4*)Tg;
  const float4* ws4 = (const float4*)ws;
  float4* o4 = (float4*)out;
  float4* dT4 = (float4*)(out + OFF_DT);

  float4 cum = {0,0,0,0}, sumT = {0,0,0,0};
  float4 Tm = {0,0,0,0}, Tc = T4[i4];

  #pragma unroll
  for (int k = 0; k < Kz; ++k) {
    float4 Tp = (k < Kz - 1) ? T4[(k + 1) * (HW / 4) + i4] : make_float4(0,0,0,0);
    float4 wa = ws4[k * (HW / 2) + 2 * i4];
    float4 wb = ws4[k * (HW / 2) + 2 * i4 + 1];
    float om0 = fmaf(0.5f, wa.x, cum.x); cum.x += wa.x;
    float om1 = fmaf(0.5f, wa.z, cum.y); cum.y += wa.z;
    float om2 = fmaf(0.5f, wb.x, cum.z); cum.z += wb.x;
    float om3 = fmaf(0.5f, wb.z, cum.w); cum.w += wb.z;

    float4 dTdp;
    if (k == 0) {
      float idp = 1.f / (pl[1] - pl[0]);
      dTdp.x = (Tp.x - Tc.x) * idp; dTdp.y = (Tp.y - Tc.y) * idp;
      dTdp.z = (Tp.z - Tc.z) * idp; dTdp.w = (Tp.w - Tc.w) * idp;
    } else if (k == Kz - 1) {
      float idp = 1.f / (pl[Kz - 1] - pl[Kz - 2]);
      dTdp.x = (Tc.x - Tm.x) * idp; dTdp.y = (Tc.y - Tm.y) * idp;
      dTdp.z = (Tc.z - Tm.z) * idp; dTdp.w = (Tc.w - Tm.w) * idp;
    } else {
      float idp = 1.f / (pl[k + 1] - pl[k - 1]);
      dTdp.x = (Tp.x - Tm.x) * idp; dTdp.y = (Tp.y - Tm.y) * idp;
      dTdp.z = (Tp.z - Tm.z) * idp; dTdp.w = (Tp.w - Tm.w) * idp;
    }
    float iplk = RCP / pl[k];
    float4 dt = dT4[k * (HW / 4) + i4];
    dt.x += om0 * fmaf(iplk, Tc.x, -dTdp.x);
    dt.y += om1 * fmaf(iplk, Tc.y, -dTdp.y);
    dt.z += om2 * fmaf(iplk, Tc.z, -dTdp.z);
    dt.w += om3 * fmaf(iplk, Tc.w, -dTdp.w);
    dT4[k * (HW / 4) + i4] = dt;

    float4 oa = o4[k * (HW / 2) + 2 * i4];
    float4 ob = o4[k * (HW / 2) + 2 * i4 + 1];
    oa.y += sumT.x; oa.w += sumT.y;
    ob.y += sumT.z; ob.w += sumT.w;
    o4[k * (HW / 2) + 2 * i4] = oa;
    o4[k * (HW / 2) + 2 * i4 + 1] = ob;

    if (k < Kz - 1) {
      float c = -287.0f * logf(pl[k] / pl[k + 1]) * invR;
      sumT.x = fmaf(c, wa.y, sumT.x);
      sumT.y = fmaf(c, wa.w, sumT.y);
      sumT.z = fmaf(c, wb.y, sumT.z);
      sumT.w = fmaf(c, wb.w, sumT.w);
    }
    Tm = Tc; Tc = Tp;
  }
}

// ------------------------------------------------- fallback fused kernel ----
constexpr int FTH = 16, FTW = 16;
constexpr int FSH = FTH + 8, FSW = FTW + 8;
constexpr int FEH = FTH + 4, FEW = FTW + 4;
constexpr int FSWp = FSW + 1, FEWp = FEW + 1;

__global__ __launch_bounds__(256) void pe_step(
    const float2* __restrict__ uv,
    const float*  __restrict__ Tg,
    const float*  __restrict__ qg,
    const float*  __restrict__ psi,
    const float*  __restrict__ quad,
    const float*  __restrict__ f_cor,
    const float*  __restrict__ p_levels,
    const float*  __restrict__ delta_p,
    float* __restrict__ out)
{
  __shared__ float uS[FSH][FSWp], vS[FSH][FSWp], TS[FSH][FSWp], qS[FSH][FSWp];
  __shared__ float keS[FEH][FEWp];
  __shared__ float d1uS[FEH][FEWp], d1vS[FEH][FEWp], d1TS[FEH][FEWp], d1qS[FEH][FEWp];
  __shared__ float P1L[FEH][25];
  __shared__ float P0L[FTH][25];
  __shared__ float quadA[FSH];
  __shared__ float pl[8], dps[8];

  const int tid = threadIdx.x;
  const int tx = tid & (FTW - 1);
  const int ty = tid >> 4;
  const int w0 = blockIdx.x * FTW;
  const int h0 = blockIdx.y * FTH;

  if (tid < FSH) quadA[tid] = quad[clipH(h0 + tid - 4)];
  if (tid < 8) { pl[tid] = p_levels[tid]; dps[tid] = delta_p[tid]; }
  for (int idx = tid; idx < FEH * 25; idx += 256) {
    int ee = idx / 25, t = idx - ee * 25;
    int p = clipH(h0 + ee - 2);
    float s = 0.f;
    #pragma unroll
    for (int kk = 0; kk < 5; ++kk)
      s += psi[kk * (2 * Hh * 25) + Hh * 25 + p * 25 + t];
    P1L[ee][t] = s;
  }
  for (int idx = tid; idx < FTH * 25; idx += 256) {
    int r = idx / 25, t = idx - r * 25;
    int p = clipH(h0 + r);
    float s = 0.f;
    #pragma unroll
    for (int kk = 0; kk < 5; ++kk)
      s += psi[kk * (2 * Hh * 25) + p * 25 + t];
    P0L[r][t] = s;
  }
  __syncthreads();

  const int h = h0 + ty;
  const bool act = h < Hh;
  const int hc = act ? h : (Hh - 1);
  const int w = w0 + tx;
  const float f = f_cor[hc];
  const float invR = (float)(1.0 / 6371000.0);
  const float cL = 200000.0f * invR * invR;
  const float RCP = (float)(287.0 / 1004.0);

  float cum = 0.f;
  float sumT = 0.f;

  #pragma unroll 1
  for (int k = 0; k < Kz; ++k) {
    __syncthreads();
    for (int idx = tid; idx < FSH * FSW; idx += 256) {
      int rr = idx / FSW, cc = idx - rr * FSW;
      int pr = clipH(h0 + rr - 4);
      int pc = w0 + cc - 4;
      pc = pc < 0 ? pc + Ww : (pc >= Ww ? pc - Ww : pc);
      int g = (k * Hh + pr) * Ww + pc;
      float2 uvv = uv[g];
      uS[rr][cc] = uvv.x; vS[rr][cc] = uvv.y;
      TS[rr][cc] = Tg[g]; qS[rr][cc] = qg[g];
    }
    __syncthreads();
    for (int idx = tid; idx < FEH * FEW; idx += 256) {
      int ee = idx / FEW, ec = idx - ee * FEW;
      float su = uS[ee + 2][ec + 2], sv = vS[ee + 2][ec + 2];
      keS[ee][ec] = 0.5f * (su * su + sv * sv);
    }
    for (int idx = tid; idx < FEH * FEW; idx += 256) {
      int ee = idx / FEW, ec = idx - ee * FEW;
      int p = clipH(h0 + ee - 2);
      float au = 0.f, av = 0.f, aT = 0.f, aq = 0.f;
      #pragma unroll
      for (int dl = 0; dl < 5; ++dl) {
        int sp = clipH(p + dl - 2);
        int rr = sp - h0 + 4;
        float qv = quadA[rr];
        float ru = 0.f, rv = 0.f, rT = 0.f, rq = 0.f;
        #pragma unroll
        for (int dw = 0; dw < 5; ++dw) {
          float wgt = P1L[ee][dl * 5 + dw];
          ru = fmaf(wgt, uS[rr][ec + dw], ru);
          rv = fmaf(wgt, vS[rr][ec + dw], rv);
          rT = fmaf(wgt, TS[rr][ec + dw], rT);
          rq = fmaf(wgt, qS[rr][ec + dw], rq);
        }
        au = fmaf(qv, ru, au); av = fmaf(qv, rv, av);
        aT = fmaf(qv, rT, aT); aq = fmaf(qv, rq, aq);
      }
      d1uS[ee][ec] = au; d1vS[ee][ec] = av;
      d1TS[ee][ec] = aT; d1qS[ee][ec] = aq;
    }
    __syncthreads();

    float d0u = 0.f, d1ke = 0.f;
    #pragma unroll
    for (int dl = 0; dl < 5; ++dl) {
      int sp = clipH(hc + dl - 2);
      int rr = sp - h0 + 4;
      int er = sp - h0 + 2;
      float qv = quadA[rr];
      float r0 = 0.f, rk = 0.f;
      #pragma unroll
      for (int dw = 0; dw < 5; ++dw) {
        r0 = fmaf(P0L[ty][dl * 5 + dw], uS[rr][tx + 2 + dw], r0);
        rk = fmaf(P1L[ty + 2][dl * 5 + dw], keS[er][tx + dw], rk);
      }
      d0u = fmaf(qv, r0, d0u);
      d1ke = fmaf(qv, rk, d1ke);
    }

    float lapu = 0.f, lapv = 0.f, lapT = 0.f, lapq = 0.f;
    #pragma unroll
    for (int dl = 0; dl < 5; ++dl) {
      int sp = clipH(hc + dl - 2);
      int er = sp - h0 + 2;
      float qv = quadA[er + 2];
      float ru = 0.f, rv = 0.f, rT = 0.f, rq = 0.f;
      #pragma unroll
      for (int dw = 0; dw < 5; ++dw) {
        float wgt = P1L[ty + 2][dl * 5 + dw];
        ru = fmaf(wgt, d1uS[er][tx + dw], ru);
        rv = fmaf(wgt, d1vS[er][tx + dw], rv);
        rT = fmaf(wgt, d1TS[er][tx + dw], rT);
        rq = fmaf(wgt, d1qS[er][tx + dw], rq);
      }
      lapu = fmaf(qv, ru, lapu); lapv = fmaf(qv, rv, lapv);
      lapT = fmaf(qv, rT, lapT); lapq = fmaf(qv, rq, lapq);
    }

    float d1T_c = d1TS[ty + 2][tx + 2];
    float d1v_c = d1vS[ty + 2][tx + 2];
    float d1q_c = d1qS[ty + 2][tx + 2];
    float uc = uS[ty + 4][tx + 4], vc = vS[ty + 4][tx + 4];
    float Tc = TS[ty + 4][tx + 4];

    float coef1 = fmaf(d0u, invR, -f);
    float duv0 = fmaf(-coef1, vc, cL * lapu);
    float yv1 = fmaf(-invR, d1ke, sumT);
    float duv1 = fmaf(coef1, uc, yv1) + cL * lapv;

    float div = invR * d1v_c;
    float dpk = dps[k];
    float omega = fmaf(0.5f * div, dpk, cum);
    cum = fmaf(div, dpk, cum);

    int gidx = (k * Hh + hc) * Ww + w;
    float dTdp;
    if (k == 0) {
      float Tp = Tg[gidx + HW];
      dTdp = (Tp - Tc) / (pl[1] - pl[0]);
    } else if (k == Kz - 1) {
      float Tm = Tg[gidx - HW];
      dTdp = (Tc - Tm) / (pl[Kz - 1] - pl[Kz - 2]);
    } else {
      float Tp = Tg[gidx + HW];
      float Tm = Tg[gidx - HW];
      dTdp = (Tp - Tm) / (pl[k + 1] - pl[k - 1]);
    }
    float adv = -(invR * d1T_c) * vc;
    float dT = adv + omega * ((RCP * Tc) / pl[k] - dTdp) + cL * lapT;
    float dq = fmaf(-(invR * d1q_c), vc, cL * lapq);

    if (act) {
      ((float2*)out)[(k * Hh + h) * Ww + w] = make_float2(duv0, duv1);
      out[OFF_DT + gidx] = dT;
      out[OFF_DQ + gidx] = dq;
    }

    if (k < Kz - 1) {
      float lpr = logf(pl[k] / pl[k + 1]);
      float wTk = (float)(-287.0 * (double)lpr / 6371000.0);
      sumT = fmaf(wTk, d1T_c, sumT);
    }
  }
}

extern "C" void kernel_launch(void* const* d_in, const int* in_sizes, int n_in,
                              void* d_out, int out_size, void* d_ws, size_t ws_size,
                              hipStream_t stream) {
  (void)in_sizes; (void)n_in; (void)out_size;
  const float2* uv   = (const float2*)d_in[0];
  const float*  T    = (const float*) d_in[1];
  const float*  q    = (const float*) d_in[2];
  const float*  psi  = (const float*) d_in[3];
  const float*  quad = (const float*) d_in[4];
  const float*  fc   = (const float*) d_in[5];
  const float*  pl   = (const float*) d_in[6];
  const float*  dp   = (const float*) d_in[7];

  const size_t ws_div_floats = (size_t)2 * Kz * HW;        // K*HW float2
  const size_t pq_floats = (size_t)Hh * PQROW;             // 14440
  const size_t ws_need = (ws_div_floats + 2 * pq_floats) * sizeof(float);
  if (ws_size >= ws_need) {
    float* wsF = (float*)d_ws;
    float* P0g = wsF + ws_div_floats;
    float* P1g = P0g + pq_floats;

    dim3 gt1((Hh * PQROW + 255) / 256);                    // 57 blocks
    hipLaunchKernelGGL(pe_tab_pq, gt1, dim3(256), 0, stream, psi, quad, P0g, P1g);

    dim3 g1(GX, (Hh + TH - 1) / TH, Kz);                   // 23 x 23 x 8
    hipLaunchKernelGGL(pe_pass1, g1, dim3(NTHR), 0, stream,
                       uv, T, q, P0g, P1g, fc, dp, (float*)d_out, (float2*)d_ws);

    dim3 g2((HW / 4 + 255) / 256);
    hipLaunchKernelGGL(pe_pass2, g2, dim3(256), 0, stream,
                       T, pl, (const float2*)d_ws, (float*)d_out);
  } else {
    dim3 grid(Ww / FTW, (Hh + FTH - 1) / FTH);
    hipLaunchKernelGGL(pe_step, grid, dim3(256), 0, stream,
                       uv, T, q, psi, quad, fc, pl, dp, (float*)d_out);
  }
}